// Round 4
// baseline (1277.790 us; speedup 1.0000x reference)
//
#include <hip/hip_runtime.h>
#include <math.h>

#define N_NODES 100000
#define N_EDGES 3200000
#define D_FEAT 128
#define H1 32
#define H2 16
#define NC 8

#define NBUCK 391          // buckets of 256 dst nodes: ceil(100000/256)
#define BCAP 16384         // fixed ebuf slots per bucket
#define EPB 4096           // edges per k_bscatter block (4 blocks/CU)
#define EPT 8              // edges per thread (EPB / 512)

typedef short s16x8 __attribute__((ext_vector_type(8)));
typedef float f32x4 __attribute__((ext_vector_type(4)));

// bf16 helpers (round-to-nearest-even pack, shift-expand)
__device__ inline unsigned short f2bf(float f) {
    unsigned int u = __float_as_uint(f);
    u += 0x7FFF + ((u >> 16) & 1);
    return (unsigned short)(u >> 16);
}
__device__ inline float bf2f(unsigned short h) {
    return __uint_as_float((unsigned int)h << 16);
}

// 64-lane inclusive scan, no barriers
__device__ inline int wave_scan_incl(int v, int lane) {
#pragma unroll
    for (int off = 1; off < 64; off <<= 1) {
        const int t = __shfl_up(v, off, 64);
        if (lane >= off) v += t;
    }
    return v;
}

// ---------------- pass A: bucket scatter via block-local LDS counting sort ---
// Folds in: per-block is64 detection, global per-node degree atomics, and
// (block 0 only) W1 bf16 MFMA-fragment prep. ebuf output is bucket-grouped
// (NOT sorted within bucket) -- that is all the pulls need.

__global__ __launch_bounds__(512) void k_bscatter(const int* __restrict__ ei,
                                                  const float* __restrict__ W1,
                                                  int* __restrict__ bucket_cursor,
                                                  int* __restrict__ deg,
                                                  unsigned short* __restrict__ W1f,
                                                  int* __restrict__ ebuf) {
    __shared__ int hist[NBUCK];
    __shared__ int lofs[NBUCK];
    __shared__ int rank[NBUCK];
    __shared__ int gb[NBUCK];
    __shared__ int wsum[8];
    __shared__ int s_is64;
    __shared__ int pay[EPB];                 // 16 KB
    __shared__ unsigned short pbk[EPB];      // 8 KB
    const int tid = threadIdx.x;
    const int lane = tid & 63;
    const int wid = tid >> 6;
    for (int i = tid; i < NBUCK; i += 512) { hist[i] = 0; rank[i] = 0; }
    if (tid < 64) {                          // wave-local is64 detect (64 samples)
        int v = ei[2 * tid + 1];
#pragma unroll
        for (int off = 1; off < 64; off <<= 1) v |= __shfl_xor(v, off, 64);
        if (tid == 0) s_is64 = (v == 0) ? 1 : 0;
    }
    if (blockIdx.x == 0) {                   // W1 MFMA B-fragment prep
        for (int idx = tid; idx < 2 * 4 * 64 * 8; idx += 512) {
            const int j    = idx & 7;
            const int ln   = (idx >> 3) & 63;
            const int kk   = (idx >> 9) & 3;
            const int nt   = idx >> 11;
            const int k = kk * 32 + ((ln >> 4) << 3) + j;
            const int n = nt * 16 + (ln & 15);
            W1f[idx] = f2bf(W1[k * H1 + n]);
        }
    }
    __syncthreads();
    const int e0 = blockIdx.x * EPB;
    const int n = min(EPB, N_EDGES - e0);    // always even (N_EDGES % 2 == 0)
    const bool is64 = (s_is64 != 0);
    int rs[EPT], rd[EPT];
    if (is64) {
#pragma unroll
        for (int k = 0; k < EPT / 2; ++k) {
            const int i = 2 * (tid + k * 512);
            if (i < n) {
                const int e = e0 + i;
                const int4 s = *(const int4*)&ei[2 * e];
                const int4 d = *(const int4*)&ei[2 * N_EDGES + 2 * e];
                rs[2 * k] = s.x; rs[2 * k + 1] = s.z;
                rd[2 * k] = d.x; rd[2 * k + 1] = d.z;
                atomicAdd(&hist[d.x >> 8], 1);
                atomicAdd(&hist[d.z >> 8], 1);
                atomicAdd(&deg[d.x], 1);
                atomicAdd(&deg[d.z], 1);
            }
        }
    } else {
#pragma unroll
        for (int k = 0; k < EPT / 2; ++k) {
            const int i = 2 * (tid + k * 512);
            if (i < n) {
                const int e = e0 + i;
                const int2 s = *(const int2*)&ei[e];
                const int2 d = *(const int2*)&ei[N_EDGES + e];
                rs[2 * k] = s.x; rs[2 * k + 1] = s.y;
                rd[2 * k] = d.x; rd[2 * k + 1] = d.y;
                atomicAdd(&hist[d.x >> 8], 1);
                atomicAdd(&hist[d.y >> 8], 1);
                atomicAdd(&deg[d.x], 1);
                atomicAdd(&deg[d.y], 1);
            }
        }
    }
    __syncthreads();
    const int own = (tid < NBUCK) ? hist[tid] : 0;
    int incl = wave_scan_incl(own, lane);
    if (lane == 63) wsum[wid] = incl;
    __syncthreads();
    if (tid == 0) {
        int r = 0;
#pragma unroll
        for (int w = 0; w < 8; ++w) { const int t = wsum[w]; wsum[w] = r; r += t; }
    }
    __syncthreads();
    incl += wsum[wid];
    if (tid < NBUCK) {
        lofs[tid] = incl - own;
        if (own > 0) gb[tid] = tid * BCAP + atomicAdd(&bucket_cursor[tid], own);
    }
    __syncthreads();
#pragma unroll
    for (int k = 0; k < EPT / 2; ++k) {
        const int i = 2 * (tid + k * 512);
        if (i < n) {
#pragma unroll
            for (int j = 0; j < 2; ++j) {
                const int b = rd[2 * k + j] >> 8;
                const int p = lofs[b] + atomicAdd(&rank[b], 1);
                pay[p] = (rs[2 * k + j] << 8) | (rd[2 * k + j] & 255);
                pbk[p] = (unsigned short)b;
            }
        }
    }
    __syncthreads();
    for (int p = tid; p < n; p += 512) {
        const int b = pbk[p];
        ebuf[gb[b] + (p - lofs[b])] = pay[p];
    }
}

// ---------------- layer 1 linear via MFMA: u1q = fp8( dinv * (x @ W1) ) ------

__global__ __launch_bounds__(256) void k_gemm1m(const float* __restrict__ x,
                                                const unsigned short* __restrict__ W1f,
                                                const int* __restrict__ deg,
                                                unsigned int* __restrict__ u1q) {
    __shared__ float os[4][16][33];
    const int tid = threadIdx.x;
    const int w = tid >> 6;
    const int lane = tid & 63;
    const int row0 = (blockIdx.x * 4 + w) * 16;
    const bool act = (row0 < N_NODES);
    if (act) {
        const int m = lane & 15;
        const int quad = lane >> 4;
        const s16x8* bf = (const s16x8*)W1f;
        f32x4 acc0 = {0.f, 0.f, 0.f, 0.f};
        f32x4 acc1 = {0.f, 0.f, 0.f, 0.f};
#pragma unroll
        for (int kk = 0; kk < 4; ++kk) {
            const float* xp = x + (size_t)(row0 + m) * D_FEAT + kk * 32 + quad * 8;
            const float4 p0 = ((const float4*)xp)[0];
            const float4 p1 = ((const float4*)xp)[1];
            s16x8 a;
            a[0] = (short)f2bf(p0.x); a[1] = (short)f2bf(p0.y);
            a[2] = (short)f2bf(p0.z); a[3] = (short)f2bf(p0.w);
            a[4] = (short)f2bf(p1.x); a[5] = (short)f2bf(p1.y);
            a[6] = (short)f2bf(p1.z); a[7] = (short)f2bf(p1.w);
            acc0 = __builtin_amdgcn_mfma_f32_16x16x32_bf16(a, bf[kk * 64 + lane], acc0, 0, 0, 0);
            acc1 = __builtin_amdgcn_mfma_f32_16x16x32_bf16(a, bf[(4 + kk) * 64 + lane], acc1, 0, 0, 0);
        }
#pragma unroll
        for (int r = 0; r < 4; ++r) {
            os[w][quad * 4 + r][m]      = acc0[r];
            os[w][quad * 4 + r][16 + m] = acc1[r];
        }
    }
    __syncthreads();
    if (act) {
        const int rl = lane >> 2;       // row-in-wave 0..15
        const int seg = lane & 3;       // 8-col segment
        const int row = row0 + rl;
        const float dv = rsqrtf(1.0f + (float)deg[row]);
        const float* p = &os[w][rl][seg * 8];
        unsigned int pk0 = __builtin_amdgcn_cvt_pk_fp8_f32(p[0] * dv, p[1] * dv, 0u, false);
        pk0 = __builtin_amdgcn_cvt_pk_fp8_f32(p[2] * dv, p[3] * dv, pk0, true);
        unsigned int pk1 = __builtin_amdgcn_cvt_pk_fp8_f32(p[4] * dv, p[5] * dv, 0u, false);
        pk1 = __builtin_amdgcn_cvt_pk_fp8_f32(p[6] * dv, p[7] * dv, pk1, true);
        uint2 o; o.x = pk0; o.y = pk1;
        ((uint2*)u1q)[(size_t)row * 4 + seg] = o;
    }
}

// ---------------- pull1: edge-parallel LDS scatter-accumulate + GEMM2 --------
// One block per bucket. Edges staged from ebuf; 4 lanes/edge gather the fp8
// row and atomically accumulate into padded h[256][33] (ds_add_f32, banks
// spread by stride 33). Epilogue: self-loop + dinv + bias + relu, then the
// 32->16 MLP, bf16-packed u2b write.

#define HADD8(Q, HP) do { \
    atomicAdd((HP) + 0, __builtin_amdgcn_cvt_f32_fp8((Q).x, 0)); \
    atomicAdd((HP) + 1, __builtin_amdgcn_cvt_f32_fp8((Q).x, 1)); \
    atomicAdd((HP) + 2, __builtin_amdgcn_cvt_f32_fp8((Q).x, 2)); \
    atomicAdd((HP) + 3, __builtin_amdgcn_cvt_f32_fp8((Q).x, 3)); \
    atomicAdd((HP) + 4, __builtin_amdgcn_cvt_f32_fp8((Q).y, 0)); \
    atomicAdd((HP) + 5, __builtin_amdgcn_cvt_f32_fp8((Q).y, 1)); \
    atomicAdd((HP) + 6, __builtin_amdgcn_cvt_f32_fp8((Q).y, 2)); \
    atomicAdd((HP) + 7, __builtin_amdgcn_cvt_f32_fp8((Q).y, 3)); \
} while (0)

__global__ __launch_bounds__(1024) void k_pull1s(const int* __restrict__ ebuf,
                                                 const int* __restrict__ bcnt,
                                                 const int* __restrict__ deg,
                                                 const unsigned int* __restrict__ u1q,
                                                 const float* __restrict__ b1,
                                                 const float* __restrict__ W2,
                                                 unsigned int* __restrict__ u2b) {
    __shared__ float h[256][33];    // 33.8 KB accumulators (pad 33 spreads banks)
    __shared__ int stg[2048];       // 8 KB staged packed edges
    __shared__ float Ws[H1 * H2];   // 2 KB
    const int b = blockIdx.x;
    const int tid = threadIdx.x;
    for (int i = tid; i < H1 * H2; i += 1024) Ws[i] = W2[i];
    for (int i = tid; i < 256 * 33; i += 1024) ((float*)h)[i] = 0.0f;
    const int nb = bcnt[b];
    const int rb = b * BCAP;
    const uint2* base = (const uint2*)u1q;
    const int eid = tid >> 2;       // edge slot 0..255
    const int lq = tid & 3;         // feature lane (8 fp8 each)
    for (int s0 = 0; s0 < nb; s0 += 2048) {
        const int m = min(2048, nb - s0);
        __syncthreads();            // h-zero done / prev pass readers done
        for (int j = tid; j < m; j += 1024) stg[j] = ebuf[rb + s0 + j];
        __syncthreads();
        int p = eid;
        for (; p + 256 < m; p += 512) {   // 2 edges in flight per lane
            const int pk0 = stg[p];
            const int pk1 = stg[p + 256];
            const uint2 q0 = base[(size_t)(pk0 >> 8) * 4 + lq];
            const uint2 q1 = base[(size_t)(pk1 >> 8) * 4 + lq];
            float* hp0 = &h[pk0 & 255][lq * 8];
            float* hp1 = &h[pk1 & 255][lq * 8];
            HADD8(q0, hp0);
            HADD8(q1, hp1);
        }
        if (p < m) {
            const int pk = stg[p];
            const uint2 q = base[(size_t)(pk >> 8) * 4 + lq];
            float* hp = &h[pk & 255][lq * 8];
            HADD8(q, hp);
        }
    }
    __syncthreads();
    const int v = b * 256 + eid;
    if (v < N_NODES) {              // self-loop + dinv + bias + relu (exclusive cells)
        const float dv = rsqrtf(1.0f + (float)deg[v]);
        const uint2 q = base[(size_t)v * 4 + lq];
        const float4 bb0 = ((const float4*)b1)[lq * 2];
        const float4 bb1 = ((const float4*)b1)[lq * 2 + 1];
        float* hp = &h[eid][lq * 8];
        hp[0] = fmaxf(fmaf(hp[0] + __builtin_amdgcn_cvt_f32_fp8(q.x, 0), dv, bb0.x), 0.0f);
        hp[1] = fmaxf(fmaf(hp[1] + __builtin_amdgcn_cvt_f32_fp8(q.x, 1), dv, bb0.y), 0.0f);
        hp[2] = fmaxf(fmaf(hp[2] + __builtin_amdgcn_cvt_f32_fp8(q.x, 2), dv, bb0.z), 0.0f);
        hp[3] = fmaxf(fmaf(hp[3] + __builtin_amdgcn_cvt_f32_fp8(q.x, 3), dv, bb0.w), 0.0f);
        hp[4] = fmaxf(fmaf(hp[4] + __builtin_amdgcn_cvt_f32_fp8(q.y, 0), dv, bb1.x), 0.0f);
        hp[5] = fmaxf(fmaf(hp[5] + __builtin_amdgcn_cvt_f32_fp8(q.y, 1), dv, bb1.y), 0.0f);
        hp[6] = fmaxf(fmaf(hp[6] + __builtin_amdgcn_cvt_f32_fp8(q.y, 2), dv, bb1.z), 0.0f);
        hp[7] = fmaxf(fmaf(hp[7] + __builtin_amdgcn_cvt_f32_fp8(q.y, 3), dv, bb1.w), 0.0f);
    }
    __syncthreads();
    if (v < N_NODES) {              // MLP 32->16, 4 threads/node x 4 cols
        const int j0 = lq * 4;
        const float dv = rsqrtf(1.0f + (float)deg[v]);
        float s0 = 0.f, s1 = 0.f, s2 = 0.f, s3 = 0.f;
#pragma unroll
        for (int k = 0; k < H1; ++k) {
            const float hk = h[eid][k];
            s0 = fmaf(hk, Ws[k * H2 + j0 + 0], s0);
            s1 = fmaf(hk, Ws[k * H2 + j0 + 1], s1);
            s2 = fmaf(hk, Ws[k * H2 + j0 + 2], s2);
            s3 = fmaf(hk, Ws[k * H2 + j0 + 3], s3);
        }
        uint2 o;
        o.x = (unsigned int)f2bf(s0 * dv) | ((unsigned int)f2bf(s1 * dv) << 16);
        o.y = (unsigned int)f2bf(s2 * dv) | ((unsigned int)f2bf(s3 * dv) << 16);
        ((uint2*)u2b)[(size_t)v * 4 + lq] = o;
    }
}

// ---------------- pull2: edge-parallel scatter-accumulate + classifier -------

#define HADD4(Q, HP) do { \
    atomicAdd((HP) + 0, bf2f((unsigned short)(Q).x)); \
    atomicAdd((HP) + 1, bf2f((unsigned short)((Q).x >> 16))); \
    atomicAdd((HP) + 2, bf2f((unsigned short)(Q).y)); \
    atomicAdd((HP) + 3, bf2f((unsigned short)((Q).y >> 16))); \
} while (0)

__global__ __launch_bounds__(1024) void k_pull2s(const int* __restrict__ ebuf,
                                                 const int* __restrict__ bcnt,
                                                 const int* __restrict__ deg,
                                                 const unsigned int* __restrict__ u2b,
                                                 const float* __restrict__ b2,
                                                 const float* __restrict__ Wc,
                                                 const float* __restrict__ bc,
                                                 float* __restrict__ out) {
    __shared__ float h[256][17];    // 17.4 KB
    __shared__ int stg[2048];       // 8 KB
    __shared__ float Wcs[H2 * NC];
    __shared__ float bcs[NC];
    const int b = blockIdx.x;
    const int tid = threadIdx.x;
    if (tid < H2 * NC) Wcs[tid] = Wc[tid];
    if (tid < NC) bcs[tid] = bc[tid];
    for (int i = tid; i < 256 * 17; i += 1024) ((float*)h)[i] = 0.0f;
    const int nb = bcnt[b];
    const int rb = b * BCAP;
    const uint2* base = (const uint2*)u2b;
    const int eid = tid >> 2;
    const int lq = tid & 3;         // 4 bf16 each
    for (int s0 = 0; s0 < nb; s0 += 2048) {
        const int m = min(2048, nb - s0);
        __syncthreads();
        for (int j = tid; j < m; j += 1024) stg[j] = ebuf[rb + s0 + j];
        __syncthreads();
        int p = eid;
        for (; p + 256 < m; p += 512) {
            const int pk0 = stg[p];
            const int pk1 = stg[p + 256];
            const uint2 q0 = base[(size_t)(pk0 >> 8) * 4 + lq];
            const uint2 q1 = base[(size_t)(pk1 >> 8) * 4 + lq];
            float* hp0 = &h[pk0 & 255][lq * 4];
            float* hp1 = &h[pk1 & 255][lq * 4];
            HADD4(q0, hp0);
            HADD4(q1, hp1);
        }
        if (p < m) {
            const int pk = stg[p];
            const uint2 q = base[(size_t)(pk >> 8) * 4 + lq];
            float* hp = &h[pk & 255][lq * 4];
            HADD4(q, hp);
        }
    }
    __syncthreads();
    const int v = b * 256 + eid;
    if (v < N_NODES) {              // self-loop + dinv + bias + relu
        const float dv = rsqrtf(1.0f + (float)deg[v]);
        const uint2 q = base[(size_t)v * 4 + lq];
        const float4 bb = ((const float4*)b2)[lq];
        float* hp = &h[eid][lq * 4];
        hp[0] = fmaxf(fmaf(hp[0] + bf2f((unsigned short)q.x), dv, bb.x), 0.0f);
        hp[1] = fmaxf(fmaf(hp[1] + bf2f((unsigned short)(q.x >> 16)), dv, bb.y), 0.0f);
        hp[2] = fmaxf(fmaf(hp[2] + bf2f((unsigned short)q.y), dv, bb.z), 0.0f);
        hp[3] = fmaxf(fmaf(hp[3] + bf2f((unsigned short)(q.y >> 16)), dv, bb.w), 0.0f);
    }
    __syncthreads();
    if (tid < 256) {                // classifier + log_softmax, 1 thread/node
        const int vv = b * 256 + tid;
        if (vv < N_NODES) {
            float lg[NC];
#pragma unroll
            for (int j = 0; j < NC; ++j) lg[j] = bcs[j];
#pragma unroll
            for (int k = 0; k < H2; ++k) {
                const float hk = h[tid][k];
#pragma unroll
                for (int j = 0; j < NC; ++j)
                    lg[j] = fmaf(hk, Wcs[k * NC + j], lg[j]);
            }
            float m = lg[0];
#pragma unroll
            for (int j = 1; j < NC; ++j) m = fmaxf(m, lg[j]);
            float s = 0.0f;
#pragma unroll
            for (int j = 0; j < NC; ++j) s += expf(lg[j] - m);
            const float lse = logf(s) + m;
            float4 o0, o1;
            o0.x = lg[0] - lse; o0.y = lg[1] - lse;
            o0.z = lg[2] - lse; o0.w = lg[3] - lse;
            o1.x = lg[4] - lse; o1.y = lg[5] - lse;
            o1.z = lg[6] - lse; o1.w = lg[7] - lse;
            float4* op = (float4*)(out + (size_t)vv * NC);
            op[0] = o0; op[1] = o1;
        }
    }
}

// ---------------- host launch ----------------

extern "C" void kernel_launch(void* const* d_in, const int* in_sizes, int n_in,
                              void* d_out, int out_size, void* d_ws, size_t ws_size,
                              hipStream_t stream) {
    const float* x   = (const float*)d_in[0];
    const int*   ei  = (const int*)d_in[1];
    const float* W1  = (const float*)d_in[2];
    const float* b1  = (const float*)d_in[3];
    const float* W2  = (const float*)d_in[4];
    const float* b2  = (const float*)d_in[5];
    const float* Wc  = (const float*)d_in[6];
    const float* bc  = (const float*)d_in[7];
    float* out = (float*)d_out;

    // workspace layout (int units). ~32.5 MB total.
    int*   bucket_cursor = (int*)d_ws;                      // 512
    int*   deg           = bucket_cursor + 512;             // 100000
    unsigned short* W1f  = (unsigned short*)(deg + 100000); // 4096 bf16 (2048 ints)
    unsigned int* u1q    = (unsigned int*)((int*)W1f + 2048);   // 800000 dwords
    unsigned int* u2b    = u1q + 800000;                    // 800000 dwords
    int*   ebuf          = (int*)(u2b + 800000);            // NBUCK*BCAP = 6406144

    hipMemsetAsync(bucket_cursor, 0, (512 + 100000) * sizeof(int), stream);
    k_bscatter<<<(N_EDGES + EPB - 1) / EPB, 512, 0, stream>>>(ei, W1, bucket_cursor, deg, W1f, ebuf);
    k_gemm1m<<<(N_NODES + 63) / 64, 256, 0, stream>>>(x, W1f, deg, u1q);
    k_pull1s<<<NBUCK, 1024, 0, stream>>>(ebuf, bucket_cursor, deg, u1q, b1, W2, u2b);
    k_pull2s<<<NBUCK, 1024, 0, stream>>>(ebuf, bucket_cursor, deg, u2b, b2, Wc, bc, out);
}

// Round 5
// 318.313 us; speedup vs baseline: 4.0143x; 4.0143x over previous
//
#include <hip/hip_runtime.h>
#include <math.h>

#define N_NODES 100000
#define N_EDGES 3200000
#define D_FEAT 128
#define H1 32
#define H2 16
#define NC 8

#define NBUCK 391          // buckets of 256 dst nodes: ceil(100000/256)
#define BCAP 12288         // ebuf slots per bucket (mean 8186, sigma ~90 -> +45 sigma)
#define HCAP 6144          // srt slots per half-bucket (mean 4093, sigma ~64)
#define EPB 4096           // edges per k_bscatter block
#define EPT 8              // edges per thread (EPB / 512)

#define P_NODES 32         // nodes per pull2 block
#define P_CAP 3072         // staged col_idx slots in pull2

typedef short s16x8 __attribute__((ext_vector_type(8)));
typedef float f32x4 __attribute__((ext_vector_type(4)));

// bf16 helpers (round-to-nearest-even pack, shift-expand)
__device__ inline unsigned short f2bf(float f) {
    unsigned int u = __float_as_uint(f);
    u += 0x7FFF + ((u >> 16) & 1);
    return (unsigned short)(u >> 16);
}
__device__ inline float bf2f(unsigned short h) {
    return __uint_as_float((unsigned int)h << 16);
}

// 64-lane inclusive scan, no barriers
__device__ inline int wave_scan_incl(int v, int lane) {
#pragma unroll
    for (int off = 1; off < 64; off <<= 1) {
        const int t = __shfl_up(v, off, 64);
        if (lane >= off) v += t;
    }
    return v;
}

// ---------------- pass A: bucket scatter via block-local LDS counting sort ---
// Folds in: per-block is64 detection, global per-node degree atomics, and
// (block 0 only) W1 bf16 MFMA-fragment prep.

__global__ __launch_bounds__(512) void k_bscatter(const int* __restrict__ ei,
                                                  const float* __restrict__ W1,
                                                  int* __restrict__ bucket_cursor,
                                                  int* __restrict__ deg,
                                                  unsigned short* __restrict__ W1f,
                                                  int* __restrict__ ebuf) {
    __shared__ int hist[NBUCK];
    __shared__ int lofs[NBUCK];
    __shared__ int rank[NBUCK];
    __shared__ int gb[NBUCK];
    __shared__ int wsum[8];
    __shared__ int s_is64;
    __shared__ int pay[EPB];                 // 16 KB
    __shared__ unsigned short pbk[EPB];      // 8 KB
    const int tid = threadIdx.x;
    const int lane = tid & 63;
    const int wid = tid >> 6;
    for (int i = tid; i < NBUCK; i += 512) { hist[i] = 0; rank[i] = 0; }
    if (tid < 64) {                          // wave-local is64 detect (64 samples)
        int v = ei[2 * tid + 1];
#pragma unroll
        for (int off = 1; off < 64; off <<= 1) v |= __shfl_xor(v, off, 64);
        if (tid == 0) s_is64 = (v == 0) ? 1 : 0;
    }
    if (blockIdx.x == 0) {                   // W1 MFMA B-fragment prep
        for (int idx = tid; idx < 2 * 4 * 64 * 8; idx += 512) {
            const int j    = idx & 7;
            const int ln   = (idx >> 3) & 63;
            const int kk   = (idx >> 9) & 3;
            const int nt   = idx >> 11;
            const int k = kk * 32 + ((ln >> 4) << 3) + j;
            const int n = nt * 16 + (ln & 15);
            W1f[idx] = f2bf(W1[k * H1 + n]);
        }
    }
    __syncthreads();
    const int e0 = blockIdx.x * EPB;
    const int n = min(EPB, N_EDGES - e0);    // always even (N_EDGES % 2 == 0)
    const bool is64 = (s_is64 != 0);
    int rs[EPT], rd[EPT];
    if (is64) {
#pragma unroll
        for (int k = 0; k < EPT / 2; ++k) {
            const int i = 2 * (tid + k * 512);
            if (i < n) {
                const int e = e0 + i;
                const int4 s = *(const int4*)&ei[2 * e];
                const int4 d = *(const int4*)&ei[2 * N_EDGES + 2 * e];
                rs[2 * k] = s.x; rs[2 * k + 1] = s.z;
                rd[2 * k] = d.x; rd[2 * k + 1] = d.z;
                atomicAdd(&hist[d.x >> 8], 1);
                atomicAdd(&hist[d.z >> 8], 1);
                atomicAdd(&deg[d.x], 1);
                atomicAdd(&deg[d.z], 1);
            }
        }
    } else {
#pragma unroll
        for (int k = 0; k < EPT / 2; ++k) {
            const int i = 2 * (tid + k * 512);
            if (i < n) {
                const int e = e0 + i;
                const int2 s = *(const int2*)&ei[e];
                const int2 d = *(const int2*)&ei[N_EDGES + e];
                rs[2 * k] = s.x; rs[2 * k + 1] = s.y;
                rd[2 * k] = d.x; rd[2 * k + 1] = d.y;
                atomicAdd(&hist[d.x >> 8], 1);
                atomicAdd(&hist[d.y >> 8], 1);
                atomicAdd(&deg[d.x], 1);
                atomicAdd(&deg[d.y], 1);
            }
        }
    }
    __syncthreads();
    const int own = (tid < NBUCK) ? hist[tid] : 0;
    int incl = wave_scan_incl(own, lane);
    if (lane == 63) wsum[wid] = incl;
    __syncthreads();
    if (tid == 0) {
        int r = 0;
#pragma unroll
        for (int w = 0; w < 8; ++w) { const int t = wsum[w]; wsum[w] = r; r += t; }
    }
    __syncthreads();
    incl += wsum[wid];
    if (tid < NBUCK) {
        lofs[tid] = incl - own;
        if (own > 0) gb[tid] = tid * BCAP + atomicAdd(&bucket_cursor[tid], own);
    }
    __syncthreads();
#pragma unroll
    for (int k = 0; k < EPT / 2; ++k) {
        const int i = 2 * (tid + k * 512);
        if (i < n) {
#pragma unroll
            for (int j = 0; j < 2; ++j) {
                const int b = rd[2 * k + j] >> 8;
                const int p = lofs[b] + atomicAdd(&rank[b], 1);
                pay[p] = (rs[2 * k + j] << 8) | (rd[2 * k + j] & 255);
                pbk[p] = (unsigned short)b;
            }
        }
    }
    __syncthreads();
    for (int p = tid; p < n; p += 512) {
        const int b = pbk[p];
        ebuf[gb[b] + (p - lofs[b])] = pay[p];
    }
}

// ---------------- layer 1 linear via MFMA: u1q = fp8( dinv * (x @ W1) ) ------

__global__ __launch_bounds__(256) void k_gemm1m(const float* __restrict__ x,
                                                const unsigned short* __restrict__ W1f,
                                                const int* __restrict__ deg,
                                                unsigned int* __restrict__ u1q) {
    __shared__ float os[4][16][33];
    const int tid = threadIdx.x;
    const int w = tid >> 6;
    const int lane = tid & 63;
    const int row0 = (blockIdx.x * 4 + w) * 16;
    const bool act = (row0 < N_NODES);
    if (act) {
        const int m = lane & 15;
        const int quad = lane >> 4;
        const s16x8* bf = (const s16x8*)W1f;
        f32x4 acc0 = {0.f, 0.f, 0.f, 0.f};
        f32x4 acc1 = {0.f, 0.f, 0.f, 0.f};
#pragma unroll
        for (int kk = 0; kk < 4; ++kk) {
            const float* xp = x + (size_t)(row0 + m) * D_FEAT + kk * 32 + quad * 8;
            const float4 p0 = ((const float4*)xp)[0];
            const float4 p1 = ((const float4*)xp)[1];
            s16x8 a;
            a[0] = (short)f2bf(p0.x); a[1] = (short)f2bf(p0.y);
            a[2] = (short)f2bf(p0.z); a[3] = (short)f2bf(p0.w);
            a[4] = (short)f2bf(p1.x); a[5] = (short)f2bf(p1.y);
            a[6] = (short)f2bf(p1.z); a[7] = (short)f2bf(p1.w);
            acc0 = __builtin_amdgcn_mfma_f32_16x16x32_bf16(a, bf[kk * 64 + lane], acc0, 0, 0, 0);
            acc1 = __builtin_amdgcn_mfma_f32_16x16x32_bf16(a, bf[(4 + kk) * 64 + lane], acc1, 0, 0, 0);
        }
#pragma unroll
        for (int r = 0; r < 4; ++r) {
            os[w][quad * 4 + r][m]      = acc0[r];
            os[w][quad * 4 + r][16 + m] = acc1[r];
        }
    }
    __syncthreads();
    if (act) {
        const int rl = lane >> 2;       // row-in-wave 0..15
        const int seg = lane & 3;       // 8-col segment
        const int row = row0 + rl;
        const float dv = rsqrtf(1.0f + (float)deg[row]);
        const float* p = &os[w][rl][seg * 8];
        unsigned int pk0 = __builtin_amdgcn_cvt_pk_fp8_f32(p[0] * dv, p[1] * dv, 0u, false);
        pk0 = __builtin_amdgcn_cvt_pk_fp8_f32(p[2] * dv, p[3] * dv, pk0, true);
        unsigned int pk1 = __builtin_amdgcn_cvt_pk_fp8_f32(p[4] * dv, p[5] * dv, 0u, false);
        pk1 = __builtin_amdgcn_cvt_pk_fp8_f32(p[6] * dv, p[7] * dv, pk1, true);
        uint2 o; o.x = pk0; o.y = pk1;
        ((uint2*)u1q)[(size_t)row * 4 + seg] = o;
    }
}

// ---------------- fused sort + pull1 + GEMM2 ---------------------------------
// Block = half-bucket (782 blocks x 512 thr). Full-bucket histogram+scan in
// LDS (2 atomics/edge), scatter own half's edges sorted into srt, write
// col_idx/row_ptr for pull2, then per-node 4-lane 8-deep register gather of
// u1q rows via srt (LDS broadcast), epilogue MLP as in R3.

#define ACC8(Q) do { \
    a0 += __builtin_amdgcn_cvt_f32_fp8((Q).x, 0); \
    a1 += __builtin_amdgcn_cvt_f32_fp8((Q).x, 1); \
    a2 += __builtin_amdgcn_cvt_f32_fp8((Q).x, 2); \
    a3 += __builtin_amdgcn_cvt_f32_fp8((Q).x, 3); \
    a4 += __builtin_amdgcn_cvt_f32_fp8((Q).y, 0); \
    a5 += __builtin_amdgcn_cvt_f32_fp8((Q).y, 1); \
    a6 += __builtin_amdgcn_cvt_f32_fp8((Q).y, 2); \
    a7 += __builtin_amdgcn_cvt_f32_fp8((Q).y, 3); \
} while (0)

__global__ __launch_bounds__(512) void k_fuse1(const int* __restrict__ ebuf,
                                               const int* __restrict__ bucket_cursor,
                                               const unsigned int* __restrict__ u1q,
                                               const float* __restrict__ b1,
                                               const float* __restrict__ W2,
                                               int* __restrict__ row_ptr,
                                               int* __restrict__ col_idx,
                                               unsigned int* __restrict__ u2b) {
    __shared__ int srt[HCAP];       // 24 KB sorted src of own half
    __shared__ int cnt[256];
    __shared__ int cur[256];
    __shared__ int wsum[8];
    __shared__ int wsum2[4];
    __shared__ float Ws[H1 * H2];   // 2 KB
    __shared__ float hs[128][33];   // 16.9 KB
    __shared__ int s_wb, s_base, s_nh;
    const int b = blockIdx.x >> 1;
    const int h = blockIdx.x & 1;
    const int tid = threadIdx.x;
    const int lane = tid & 63;
    const int wid = tid >> 6;
    if (tid < 256) cnt[tid] = 0;
    for (int i = tid; i < H1 * H2; i += 512) Ws[i] = W2[i];
    // cross-bucket exclusive scan of final bucket counts -> wb
    const int own0 = (tid < NBUCK) ? bucket_cursor[tid] : 0;
    int incl0 = wave_scan_incl(own0, lane);
    if (lane == 63) wsum[wid] = incl0;
    __syncthreads();                                   // B1: wsum + cnt-zero
    if (tid == 0) {
        int r = 0;
#pragma unroll
        for (int w = 0; w < 8; ++w) { const int t = wsum[w]; wsum[w] = r; r += t; }
    }
    __syncthreads();                                   // B2: wsum merged
    if (tid == b) s_wb = incl0 + wsum[wid] - own0;
    const int nb = bucket_cursor[b];
    const int rb = b * BCAP;
    // full-bucket histogram
    for (int i = tid; i < nb; i += 512)
        atomicAdd(&cnt[ebuf[rb + i] & 255], 1);
    __syncthreads();                                   // B3: hist + s_wb done
    // 256-wide scan of cnt (waves 0..3)
    int ownc = 0, inclc = 0;
    if (tid < 256) {
        ownc = cnt[tid];
        inclc = wave_scan_incl(ownc, lane);
        if (lane == 63) wsum2[wid] = inclc;
    }
    __syncthreads();                                   // B4
    if (tid == 0) {
        int r = 0;
#pragma unroll
        for (int w = 0; w < 4; ++w) { const int t = wsum2[w]; wsum2[w] = r; r += t; }
    }
    __syncthreads();                                   // B5
    const int wb = s_wb;
    if (tid < 256) {
        inclc += wsum2[wid];
        const int excl = inclc - ownc;
        cur[tid] = excl;
        const int v = (b << 8) + tid;
        if (v <= N_NODES) row_ptr[v] = wb + excl;      // covers row_ptr[N_NODES]
    }
    __syncthreads();                                   // B6: cur=excl ready
    if (tid == 0) {
        s_base = cur[h * 128];                         // half's first global slot
        s_nh = (h ? nb : cur[128]) - cur[h * 128];     // edges in this half
    }
    __syncthreads();                                   // B7: s_base/s_nh ready
    const int base_h = s_base;
    const int nh = s_nh;
    // scatter own half's edges into srt (local slots), sorted by dst
    for (int i = tid; i < nb; i += 512) {
        const int pk = ebuf[rb + i];
        const int dl = pk & 255;
        if ((dl >> 7) == h) {
            const int slot = atomicAdd(&cur[dl], 1);
            srt[slot - base_h] = pk >> 8;
        }
    }
    __syncthreads();                                   // B8: srt ready, cur=incl
    // coalesced col_idx write for pull2
    for (int i = tid; i < nh; i += 512)
        col_idx[wb + base_h + i] = srt[i];
    // per-node register gather (4 lanes/node, 8-deep pipeline)
    const int nnl = tid >> 2;       // node-in-half 0..127
    const int lq = tid & 3;         // feature lane (8 fp8 = 8B each)
    const int nn = h * 128 + nnl;
    const int v = (b << 8) + nn;
    if (v < N_NODES) {
        const uint2* base = (const uint2*)u1q;
        const uint2 q = base[(size_t)v * 4 + lq];      // self-loop term
        float a0 = __builtin_amdgcn_cvt_f32_fp8(q.x, 0);
        float a1 = __builtin_amdgcn_cvt_f32_fp8(q.x, 1);
        float a2 = __builtin_amdgcn_cvt_f32_fp8(q.x, 2);
        float a3 = __builtin_amdgcn_cvt_f32_fp8(q.x, 3);
        float a4 = __builtin_amdgcn_cvt_f32_fp8(q.y, 0);
        float a5 = __builtin_amdgcn_cvt_f32_fp8(q.y, 1);
        float a6 = __builtin_amdgcn_cvt_f32_fp8(q.y, 2);
        float a7 = __builtin_amdgcn_cvt_f32_fp8(q.y, 3);
        const int cn = cnt[nn];
        const int e = cur[nn] - base_h;                // local end
        int j = e - cn;                                // local start
        for (; j + 7 < e; j += 8) {                    // 8 gathers in flight
            const int s0 = srt[j + 0];
            const int s1 = srt[j + 1];
            const int s2 = srt[j + 2];
            const int s3 = srt[j + 3];
            const int s4 = srt[j + 4];
            const int s5 = srt[j + 5];
            const int s6 = srt[j + 6];
            const int s7 = srt[j + 7];
            const uint2 q0 = base[(size_t)s0 * 4 + lq];
            const uint2 q1 = base[(size_t)s1 * 4 + lq];
            const uint2 q2 = base[(size_t)s2 * 4 + lq];
            const uint2 q3 = base[(size_t)s3 * 4 + lq];
            const uint2 q4 = base[(size_t)s4 * 4 + lq];
            const uint2 q5 = base[(size_t)s5 * 4 + lq];
            const uint2 q6 = base[(size_t)s6 * 4 + lq];
            const uint2 q7 = base[(size_t)s7 * 4 + lq];
            ACC8(q0); ACC8(q1); ACC8(q2); ACC8(q3);
            ACC8(q4); ACC8(q5); ACC8(q6); ACC8(q7);
        }
        for (; j + 3 < e; j += 4) {
            const int s0 = srt[j + 0];
            const int s1 = srt[j + 1];
            const int s2 = srt[j + 2];
            const int s3 = srt[j + 3];
            const uint2 q0 = base[(size_t)s0 * 4 + lq];
            const uint2 q1 = base[(size_t)s1 * 4 + lq];
            const uint2 q2 = base[(size_t)s2 * 4 + lq];
            const uint2 q3 = base[(size_t)s3 * 4 + lq];
            ACC8(q0); ACC8(q1); ACC8(q2); ACC8(q3);
        }
        for (; j < e; ++j) {
            const uint2 qq = base[(size_t)srt[j] * 4 + lq];
            ACC8(qq);
        }
        const float dv = rsqrtf(1.0f + (float)cn);
        const float4 bb0 = ((const float4*)b1)[lq * 2];
        const float4 bb1 = ((const float4*)b1)[lq * 2 + 1];
        float* hp = &hs[nnl][lq * 8];
        hp[0] = fmaxf(fmaf(a0, dv, bb0.x), 0.0f);
        hp[1] = fmaxf(fmaf(a1, dv, bb0.y), 0.0f);
        hp[2] = fmaxf(fmaf(a2, dv, bb0.z), 0.0f);
        hp[3] = fmaxf(fmaf(a3, dv, bb0.w), 0.0f);
        hp[4] = fmaxf(fmaf(a4, dv, bb1.x), 0.0f);
        hp[5] = fmaxf(fmaf(a5, dv, bb1.y), 0.0f);
        hp[6] = fmaxf(fmaf(a6, dv, bb1.z), 0.0f);
        hp[7] = fmaxf(fmaf(a7, dv, bb1.w), 0.0f);
        if (lq == 0) hs[nnl][32] = dv;
    }
    __syncthreads();                                   // B9: hs ready
    {
        const int nn2 = tid >> 2;
        const int jq = tid & 3;
        const int v2 = (b << 8) + h * 128 + nn2;
        if (v2 < N_NODES) {
            const int j0 = jq * 4;
            const float dv = hs[nn2][32];
            float s0 = 0.f, s1 = 0.f, s2 = 0.f, s3 = 0.f;
#pragma unroll
            for (int k = 0; k < H1; ++k) {
                const float hk = hs[nn2][k];
                s0 = fmaf(hk, Ws[k * H2 + j0 + 0], s0);
                s1 = fmaf(hk, Ws[k * H2 + j0 + 1], s1);
                s2 = fmaf(hk, Ws[k * H2 + j0 + 2], s2);
                s3 = fmaf(hk, Ws[k * H2 + j0 + 3], s3);
            }
            uint2 o;
            o.x = (unsigned int)f2bf(s0 * dv) | ((unsigned int)f2bf(s1 * dv) << 16);
            o.y = (unsigned int)f2bf(s2 * dv) | ((unsigned int)f2bf(s3 * dv) << 16);
            ((uint2*)u2b)[(size_t)v2 * 4 + jq] = o;
        }
    }
}

// ---------------- fused pull2 + classifier (R3 structure) --------------------

#define ACC4(Q) do { \
    a0 += bf2f((unsigned short)(Q).x); \
    a1 += bf2f((unsigned short)((Q).x >> 16)); \
    a2 += bf2f((unsigned short)(Q).y); \
    a3 += bf2f((unsigned short)((Q).y >> 16)); \
} while (0)

__global__ __launch_bounds__(256) void k_pull2f(const int* __restrict__ row_ptr,
                                                const int* __restrict__ col_idx,
                                                const int* __restrict__ deg,
                                                const unsigned int* __restrict__ u2b,
                                                const float* __restrict__ b2,
                                                const float* __restrict__ Wc,
                                                const float* __restrict__ bc,
                                                float* __restrict__ out) {
    __shared__ float hs[P_NODES][17];
    __shared__ float Wcs[H2 * NC];  // 128
    __shared__ float bcs[NC];
    __shared__ int lidx[P_CAP];     // 12 KB
    const int tid = threadIdx.x;
    if (tid < H2 * NC) Wcs[tid] = Wc[tid];
    if (tid < NC) bcs[tid] = bc[tid];
    const int v0 = blockIdx.x * P_NODES;
    const int base_off = row_ptr[v0];
    const int range = row_ptr[v0 + P_NODES] - base_off;
    const bool ovf = (range > P_CAP);
    const int stg = ovf ? 0 : range;
    for (int j = tid; j < stg; j += 256) lidx[j] = col_idx[base_off + j];
    __syncthreads();
    const int n = tid >> 3;
    const int half = (tid >> 2) & 1;
    const int lq = tid & 3;
    const int v = v0 + n;
    const uint2* base = (const uint2*)u2b;
    float a0 = 0.f, a1 = 0.f, a2 = 0.f, a3 = 0.f;
    if (half == 0) {
        const uint2 q = base[(size_t)v * 4 + lq];
        a0 = bf2f((unsigned short)q.x); a1 = bf2f((unsigned short)(q.x >> 16));
        a2 = bf2f((unsigned short)q.y); a3 = bf2f((unsigned short)(q.y >> 16));
    }
    const int beg = row_ptr[v] - base_off;
    const int end = row_ptr[v + 1] - base_off;
    int i = beg + half;
    if (!ovf) {
        for (; i + 14 < end; i += 16) {
            const int s0 = lidx[i];
            const int s1 = lidx[i + 2];
            const int s2 = lidx[i + 4];
            const int s3 = lidx[i + 6];
            const int s4 = lidx[i + 8];
            const int s5 = lidx[i + 10];
            const int s6 = lidx[i + 12];
            const int s7 = lidx[i + 14];
            const uint2 q0 = base[(size_t)s0 * 4 + lq];
            const uint2 q1 = base[(size_t)s1 * 4 + lq];
            const uint2 q2 = base[(size_t)s2 * 4 + lq];
            const uint2 q3 = base[(size_t)s3 * 4 + lq];
            const uint2 q4 = base[(size_t)s4 * 4 + lq];
            const uint2 q5 = base[(size_t)s5 * 4 + lq];
            const uint2 q6 = base[(size_t)s6 * 4 + lq];
            const uint2 q7 = base[(size_t)s7 * 4 + lq];
            ACC4(q0); ACC4(q1); ACC4(q2); ACC4(q3);
            ACC4(q4); ACC4(q5); ACC4(q6); ACC4(q7);
        }
        for (; i + 6 < end; i += 8) {
            const int s0 = lidx[i];
            const int s1 = lidx[i + 2];
            const int s2 = lidx[i + 4];
            const int s3 = lidx[i + 6];
            const uint2 q0 = base[(size_t)s0 * 4 + lq];
            const uint2 q1 = base[(size_t)s1 * 4 + lq];
            const uint2 q2 = base[(size_t)s2 * 4 + lq];
            const uint2 q3 = base[(size_t)s3 * 4 + lq];
            ACC4(q0); ACC4(q1); ACC4(q2); ACC4(q3);
        }
        for (; i < end; i += 2) {
            const uint2 qq = base[(size_t)lidx[i] * 4 + lq];
            ACC4(qq);
        }
    } else {
        const int* gp = col_idx + base_off;
        for (; i + 14 < end; i += 16) {
            const int s0 = gp[i];
            const int s1 = gp[i + 2];
            const int s2 = gp[i + 4];
            const int s3 = gp[i + 6];
            const int s4 = gp[i + 8];
            const int s5 = gp[i + 10];
            const int s6 = gp[i + 12];
            const int s7 = gp[i + 14];
            const uint2 q0 = base[(size_t)s0 * 4 + lq];
            const uint2 q1 = base[(size_t)s1 * 4 + lq];
            const uint2 q2 = base[(size_t)s2 * 4 + lq];
            const uint2 q3 = base[(size_t)s3 * 4 + lq];
            const uint2 q4 = base[(size_t)s4 * 4 + lq];
            const uint2 q5 = base[(size_t)s5 * 4 + lq];
            const uint2 q6 = base[(size_t)s6 * 4 + lq];
            const uint2 q7 = base[(size_t)s7 * 4 + lq];
            ACC4(q0); ACC4(q1); ACC4(q2); ACC4(q3);
            ACC4(q4); ACC4(q5); ACC4(q6); ACC4(q7);
        }
        for (; i < end; i += 2) {
            const uint2 qq = base[(size_t)gp[i] * 4 + lq];
            ACC4(qq);
        }
    }
    a0 += __shfl_xor(a0, 4, 64); a1 += __shfl_xor(a1, 4, 64);
    a2 += __shfl_xor(a2, 4, 64); a3 += __shfl_xor(a3, 4, 64);
    if (half == 0) {
        const float dv = rsqrtf(1.0f + (float)deg[v]);
        const float4 bb = ((const float4*)b2)[lq];
        float* hp = &hs[n][lq * 4];
        hp[0] = fmaxf(fmaf(a0, dv, bb.x), 0.0f);
        hp[1] = fmaxf(fmaf(a1, dv, bb.y), 0.0f);
        hp[2] = fmaxf(fmaf(a2, dv, bb.z), 0.0f);
        hp[3] = fmaxf(fmaf(a3, dv, bb.w), 0.0f);
    }
    __syncthreads();
    if (tid < P_NODES) {
        const int vv = v0 + tid;
        float lg[NC];
#pragma unroll
        for (int j = 0; j < NC; ++j) lg[j] = bcs[j];
#pragma unroll
        for (int k = 0; k < H2; ++k) {
            const float hk = hs[tid][k];
#pragma unroll
            for (int j = 0; j < NC; ++j)
                lg[j] = fmaf(hk, Wcs[k * NC + j], lg[j]);
        }
        float m = lg[0];
#pragma unroll
        for (int j = 1; j < NC; ++j) m = fmaxf(m, lg[j]);
        float s = 0.0f;
#pragma unroll
        for (int j = 0; j < NC; ++j) s += expf(lg[j] - m);
        const float lse = logf(s) + m;
        float4 o0, o1;
        o0.x = lg[0] - lse; o0.y = lg[1] - lse;
        o0.z = lg[2] - lse; o0.w = lg[3] - lse;
        o1.x = lg[4] - lse; o1.y = lg[5] - lse;
        o1.z = lg[6] - lse; o1.w = lg[7] - lse;
        float4* op = (float4*)(out + (size_t)vv * NC);
        op[0] = o0; op[1] = o1;
    }
}

// ---------------- host launch ----------------

extern "C" void kernel_launch(void* const* d_in, const int* in_sizes, int n_in,
                              void* d_out, int out_size, void* d_ws, size_t ws_size,
                              hipStream_t stream) {
    const float* x   = (const float*)d_in[0];
    const int*   ei  = (const int*)d_in[1];
    const float* W1  = (const float*)d_in[2];
    const float* b1  = (const float*)d_in[3];
    const float* W2  = (const float*)d_in[4];
    const float* b2  = (const float*)d_in[5];
    const float* Wc  = (const float*)d_in[6];
    const float* bc  = (const float*)d_in[7];
    float* out = (float*)d_out;

    // workspace layout (int units). ~39.2 MB total.
    int*   bucket_cursor = (int*)d_ws;                       // 512
    int*   deg           = bucket_cursor + 512;              // 100000
    unsigned short* W1f  = (unsigned short*)(deg + 100000);  // 4096 bf16 (2048 ints)
    int*   row_ptr       = (int*)W1f + 2048;                 // 100016 (100001 used)
    int*   col_idx       = row_ptr + 100016;                 // 3200000
    unsigned int* u1q    = (unsigned int*)(col_idx + 3200000); // 800000 dwords
    unsigned int* u2b    = u1q + 800000;                     // 800000 dwords
    int*   ebuf          = (int*)(u2b + 800000);             // NBUCK*BCAP = 4804608

    hipMemsetAsync(bucket_cursor, 0, (512 + 100000) * sizeof(int), stream);
    k_bscatter<<<(N_EDGES + EPB - 1) / EPB, 512, 0, stream>>>(ei, W1, bucket_cursor, deg, W1f, ebuf);
    k_gemm1m<<<(N_NODES + 63) / 64, 256, 0, stream>>>(x, W1f, deg, u1q);
    k_fuse1 <<<NBUCK * 2, 512, 0, stream>>>(ebuf, bucket_cursor, u1q, b1, W2, row_ptr, col_idx, u2b);
    k_pull2f<<<N_NODES / P_NODES, 256, 0, stream>>>(row_ptr, col_idx, deg, u2b, b2, Wc, bc, out);
}

// Round 7
// 205.263 us; speedup vs baseline: 6.2251x; 1.5508x over previous
//
#include <hip/hip_runtime.h>
#include <math.h>

#define N_NODES 100000
#define N_EDGES 3200000
#define D_FEAT 128
#define H1 32
#define H2 16
#define NC 8

#define NBUCK 391          // buckets of 256 dst nodes: ceil(100000/256)
#define BCAP 12288         // ebuf slots per bucket (mean 8186)
#define HCAP 6144          // srt slots per half-bucket (mean 4093)
#define EPB 4096           // edges per k_bscatter block
#define EPT 8              // edges per thread (EPB / 512)

#define P_NODES 32         // nodes per pull2 block
#define P_CAP 3072         // staged col_idx slots in pull2

typedef short s16x8 __attribute__((ext_vector_type(8)));
typedef float f32x4 __attribute__((ext_vector_type(4)));

// bf16 helpers (round-to-nearest-even pack, shift-expand)
__device__ inline unsigned short f2bf(float f) {
    unsigned int u = __float_as_uint(f);
    u += 0x7FFF + ((u >> 16) & 1);
    return (unsigned short)(u >> 16);
}
__device__ inline float bf2f(unsigned short h) {
    return __uint_as_float((unsigned int)h << 16);
}

// 64-lane inclusive scan, no barriers
__device__ inline int wave_scan_incl(int v, int lane) {
#pragma unroll
    for (int off = 1; off < 64; off <<= 1) {
        const int t = __shfl_up(v, off, 64);
        if (lane >= off) v += t;
    }
    return v;
}

// ---------------- pass A: bucket scatter via block-local LDS counting sort ---
// Folds in: per-block is64 detection and (block 0 only) W1 bf16 fragment prep.
// NO per-edge global atomics (R5 lesson: device-scope atomics write through
// L2 -> 105 MB extra HBM writes + latency serialization).

__global__ __launch_bounds__(512) void k_bscatter(const int* __restrict__ ei,
                                                  const float* __restrict__ W1,
                                                  int* __restrict__ bucket_cursor,
                                                  unsigned short* __restrict__ W1f,
                                                  int* __restrict__ ebuf) {
    __shared__ int hist[NBUCK];
    __shared__ int lofs[NBUCK];
    __shared__ int rank[NBUCK];
    __shared__ int gb[NBUCK];
    __shared__ int wsum[8];
    __shared__ int s_is64;
    __shared__ int pay[EPB];                 // 16 KB
    __shared__ unsigned short pbk[EPB];      // 8 KB
    const int tid = threadIdx.x;
    const int lane = tid & 63;
    const int wid = tid >> 6;
    for (int i = tid; i < NBUCK; i += 512) { hist[i] = 0; rank[i] = 0; }
    if (tid < 64) {                          // wave-local is64 detect (64 samples)
        int v = ei[2 * tid + 1];
#pragma unroll
        for (int off = 1; off < 64; off <<= 1) v |= __shfl_xor(v, off, 64);
        if (tid == 0) s_is64 = (v == 0) ? 1 : 0;
    }
    if (blockIdx.x == 0) {                   // W1 MFMA B-fragment prep
        for (int idx = tid; idx < 2 * 4 * 64 * 8; idx += 512) {
            const int j    = idx & 7;
            const int ln   = (idx >> 3) & 63;
            const int kk   = (idx >> 9) & 3;
            const int nt   = idx >> 11;
            const int k = kk * 32 + ((ln >> 4) << 3) + j;
            const int n = nt * 16 + (ln & 15);
            W1f[idx] = f2bf(W1[k * H1 + n]);
        }
    }
    __syncthreads();
    const int e0 = blockIdx.x * EPB;
    const int n = min(EPB, N_EDGES - e0);    // always even (N_EDGES % 2 == 0)
    const bool is64 = (s_is64 != 0);
    int rs[EPT], rd[EPT];
    if (is64) {
#pragma unroll
        for (int k = 0; k < EPT / 2; ++k) {
            const int i = 2 * (tid + k * 512);
            if (i < n) {
                const int e = e0 + i;
                const int4 s = *(const int4*)&ei[2 * e];
                const int4 d = *(const int4*)&ei[2 * N_EDGES + 2 * e];
                rs[2 * k] = s.x; rs[2 * k + 1] = s.z;
                rd[2 * k] = d.x; rd[2 * k + 1] = d.z;
                atomicAdd(&hist[d.x >> 8], 1);
                atomicAdd(&hist[d.z >> 8], 1);
            }
        }
    } else {
#pragma unroll
        for (int k = 0; k < EPT / 2; ++k) {
            const int i = 2 * (tid + k * 512);
            if (i < n) {
                const int e = e0 + i;
                const int2 s = *(const int2*)&ei[e];
                const int2 d = *(const int2*)&ei[N_EDGES + e];
                rs[2 * k] = s.x; rs[2 * k + 1] = s.y;
                rd[2 * k] = d.x; rd[2 * k + 1] = d.y;
                atomicAdd(&hist[d.x >> 8], 1);
                atomicAdd(&hist[d.y >> 8], 1);
            }
        }
    }
    __syncthreads();
    const int own = (tid < NBUCK) ? hist[tid] : 0;
    int incl = wave_scan_incl(own, lane);
    if (lane == 63) wsum[wid] = incl;
    __syncthreads();
    if (tid == 0) {
        int r = 0;
#pragma unroll
        for (int w = 0; w < 8; ++w) { const int t = wsum[w]; wsum[w] = r; r += t; }
    }
    __syncthreads();
    incl += wsum[wid];
    if (tid < NBUCK) {
        lofs[tid] = incl - own;
        if (own > 0) gb[tid] = tid * BCAP + atomicAdd(&bucket_cursor[tid], own);
    }
    __syncthreads();
#pragma unroll
    for (int k = 0; k < EPT / 2; ++k) {
        const int i = 2 * (tid + k * 512);
        if (i < n) {
#pragma unroll
            for (int j = 0; j < 2; ++j) {
                const int b = rd[2 * k + j] >> 8;
                const int p = lofs[b] + atomicAdd(&rank[b], 1);
                pay[p] = (rs[2 * k + j] << 8) | (rd[2 * k + j] & 255);
                pbk[p] = (unsigned short)b;
            }
        }
    }
    __syncthreads();
    for (int p = tid; p < n; p += 512) {
        const int b = pbk[p];
        ebuf[gb[b] + (p - lofs[b])] = pay[p];
    }
}

// ---------------- degree via per-bucket LDS histogram -> dinv ----------------

__global__ __launch_bounds__(512) void k_deg(const int* __restrict__ ebuf,
                                             const int* __restrict__ bucket_cursor,
                                             float* __restrict__ dinv) {
    __shared__ int cnt[256];
    const int b = blockIdx.x;
    const int tid = threadIdx.x;
    if (tid < 256) cnt[tid] = 0;
    __syncthreads();
    const int nb = bucket_cursor[b];
    const int rb = b * BCAP;
    for (int i = tid; i < nb; i += 512)
        atomicAdd(&cnt[ebuf[rb + i] & 255], 1);
    __syncthreads();
    if (tid < 256) {
        const int v = (b << 8) + tid;
        if (v < N_NODES) dinv[v] = rsqrtf(1.0f + (float)cnt[tid]);
    }
}

// ---------------- layer 1 linear via MFMA: u1q = fp8( dinv * (x @ W1) ) ------

__global__ __launch_bounds__(256) void k_gemm1m(const float* __restrict__ x,
                                                const unsigned short* __restrict__ W1f,
                                                const float* __restrict__ dinv,
                                                unsigned int* __restrict__ u1q) {
    __shared__ float os[4][16][33];
    const int tid = threadIdx.x;
    const int w = tid >> 6;
    const int lane = tid & 63;
    const int row0 = (blockIdx.x * 4 + w) * 16;
    const bool act = (row0 < N_NODES);
    if (act) {
        const int m = lane & 15;
        const int quad = lane >> 4;
        const s16x8* bf = (const s16x8*)W1f;
        f32x4 acc0 = {0.f, 0.f, 0.f, 0.f};
        f32x4 acc1 = {0.f, 0.f, 0.f, 0.f};
#pragma unroll
        for (int kk = 0; kk < 4; ++kk) {
            const float* xp = x + (size_t)(row0 + m) * D_FEAT + kk * 32 + quad * 8;
            const float4 p0 = ((const float4*)xp)[0];
            const float4 p1 = ((const float4*)xp)[1];
            s16x8 a;
            a[0] = (short)f2bf(p0.x); a[1] = (short)f2bf(p0.y);
            a[2] = (short)f2bf(p0.z); a[3] = (short)f2bf(p0.w);
            a[4] = (short)f2bf(p1.x); a[5] = (short)f2bf(p1.y);
            a[6] = (short)f2bf(p1.z); a[7] = (short)f2bf(p1.w);
            acc0 = __builtin_amdgcn_mfma_f32_16x16x32_bf16(a, bf[kk * 64 + lane], acc0, 0, 0, 0);
            acc1 = __builtin_amdgcn_mfma_f32_16x16x32_bf16(a, bf[(4 + kk) * 64 + lane], acc1, 0, 0, 0);
        }
#pragma unroll
        for (int r = 0; r < 4; ++r) {
            os[w][quad * 4 + r][m]      = acc0[r];
            os[w][quad * 4 + r][16 + m] = acc1[r];
        }
    }
    __syncthreads();
    if (act) {
        const int rl = lane >> 2;       // row-in-wave 0..15
        const int seg = lane & 3;       // 8-col segment
        const int row = row0 + rl;
        const float dv = dinv[row];
        const float* p = &os[w][rl][seg * 8];
        unsigned int pk0 = __builtin_amdgcn_cvt_pk_fp8_f32(p[0] * dv, p[1] * dv, 0u, false);
        pk0 = __builtin_amdgcn_cvt_pk_fp8_f32(p[2] * dv, p[3] * dv, pk0, true);
        unsigned int pk1 = __builtin_amdgcn_cvt_pk_fp8_f32(p[4] * dv, p[5] * dv, 0u, false);
        pk1 = __builtin_amdgcn_cvt_pk_fp8_f32(p[6] * dv, p[7] * dv, pk1, true);
        uint2 o; o.x = pk0; o.y = pk1;
        ((uint2*)u1q)[(size_t)row * 4 + seg] = o;
    }
}

// ---------------- fused sort + pull1 + GEMM2 (unchanged from R5) -------------

#define ACC8(Q) do { \
    a0 += __builtin_amdgcn_cvt_f32_fp8((Q).x, 0); \
    a1 += __builtin_amdgcn_cvt_f32_fp8((Q).x, 1); \
    a2 += __builtin_amdgcn_cvt_f32_fp8((Q).x, 2); \
    a3 += __builtin_amdgcn_cvt_f32_fp8((Q).x, 3); \
    a4 += __builtin_amdgcn_cvt_f32_fp8((Q).y, 0); \
    a5 += __builtin_amdgcn_cvt_f32_fp8((Q).y, 1); \
    a6 += __builtin_amdgcn_cvt_f32_fp8((Q).y, 2); \
    a7 += __builtin_amdgcn_cvt_f32_fp8((Q).y, 3); \
} while (0)

__global__ __launch_bounds__(512) void k_fuse1(const int* __restrict__ ebuf,
                                               const int* __restrict__ bucket_cursor,
                                               const unsigned int* __restrict__ u1q,
                                               const float* __restrict__ b1,
                                               const float* __restrict__ W2,
                                               int* __restrict__ row_ptr,
                                               int* __restrict__ col_idx,
                                               unsigned int* __restrict__ u2b) {
    __shared__ int srt[HCAP];       // 24 KB sorted src of own half
    __shared__ int cnt[256];
    __shared__ int cur[256];
    __shared__ int wsum[8];
    __shared__ int wsum2[4];
    __shared__ float Ws[H1 * H2];   // 2 KB
    __shared__ float hs[128][33];   // 16.9 KB
    __shared__ int s_wb, s_base, s_nh;
    const int b = blockIdx.x >> 1;
    const int h = blockIdx.x & 1;
    const int tid = threadIdx.x;
    const int lane = tid & 63;
    const int wid = tid >> 6;
    if (tid < 256) cnt[tid] = 0;
    for (int i = tid; i < H1 * H2; i += 512) Ws[i] = W2[i];
    // cross-bucket exclusive scan of final bucket counts -> wb
    const int own0 = (tid < NBUCK) ? bucket_cursor[tid] : 0;
    int incl0 = wave_scan_incl(own0, lane);
    if (lane == 63) wsum[wid] = incl0;
    __syncthreads();                                   // B1: wsum + cnt-zero
    if (tid == 0) {
        int r = 0;
#pragma unroll
        for (int w = 0; w < 8; ++w) { const int t = wsum[w]; wsum[w] = r; r += t; }
    }
    __syncthreads();                                   // B2: wsum merged
    if (tid == b) s_wb = incl0 + wsum[wid] - own0;
    const int nb = bucket_cursor[b];
    const int rb = b * BCAP;
    // full-bucket histogram
    for (int i = tid; i < nb; i += 512)
        atomicAdd(&cnt[ebuf[rb + i] & 255], 1);
    __syncthreads();                                   // B3: hist + s_wb done
    // 256-wide scan of cnt (waves 0..3)
    int ownc = 0, inclc = 0;
    if (tid < 256) {
        ownc = cnt[tid];
        inclc = wave_scan_incl(ownc, lane);
        if (lane == 63) wsum2[wid] = inclc;
    }
    __syncthreads();                                   // B4
    if (tid == 0) {
        int r = 0;
#pragma unroll
        for (int w = 0; w < 4; ++w) { const int t = wsum2[w]; wsum2[w] = r; r += t; }
    }
    __syncthreads();                                   // B5
    const int wb = s_wb;
    if (tid < 256) {
        inclc += wsum2[wid];
        const int excl = inclc - ownc;
        cur[tid] = excl;
        const int v = (b << 8) + tid;
        if (v <= N_NODES) row_ptr[v] = wb + excl;      // covers row_ptr[N_NODES]
    }
    __syncthreads();                                   // B6: cur=excl ready
    if (tid == 0) {
        s_base = cur[h * 128];                         // half's first global slot
        s_nh = (h ? nb : cur[128]) - cur[h * 128];     // edges in this half
    }
    __syncthreads();                                   // B7: s_base/s_nh ready
    const int base_h = s_base;
    const int nh = s_nh;
    // scatter own half's edges into srt (local slots), sorted by dst
    for (int i = tid; i < nb; i += 512) {
        const int pk = ebuf[rb + i];
        const int dl = pk & 255;
        if ((dl >> 7) == h) {
            const int slot = atomicAdd(&cur[dl], 1);
            srt[slot - base_h] = pk >> 8;
        }
    }
    __syncthreads();                                   // B8: srt ready, cur=incl
    // coalesced col_idx write for pull2
    for (int i = tid; i < nh; i += 512)
        col_idx[wb + base_h + i] = srt[i];
    // per-node register gather (4 lanes/node, 8-deep pipeline)
    const int nnl = tid >> 2;       // node-in-half 0..127
    const int lq = tid & 3;         // feature lane (8 fp8 = 8B each)
    const int nn = h * 128 + nnl;
    const int v = (b << 8) + nn;
    if (v < N_NODES) {
        const uint2* base = (const uint2*)u1q;
        const uint2 q = base[(size_t)v * 4 + lq];      // self-loop term
        float a0 = __builtin_amdgcn_cvt_f32_fp8(q.x, 0);
        float a1 = __builtin_amdgcn_cvt_f32_fp8(q.x, 1);
        float a2 = __builtin_amdgcn_cvt_f32_fp8(q.x, 2);
        float a3 = __builtin_amdgcn_cvt_f32_fp8(q.x, 3);
        float a4 = __builtin_amdgcn_cvt_f32_fp8(q.y, 0);
        float a5 = __builtin_amdgcn_cvt_f32_fp8(q.y, 1);
        float a6 = __builtin_amdgcn_cvt_f32_fp8(q.y, 2);
        float a7 = __builtin_amdgcn_cvt_f32_fp8(q.y, 3);
        const int cn = cnt[nn];
        const int e = cur[nn] - base_h;                // local end
        int j = e - cn;                                // local start
        for (; j + 7 < e; j += 8) {                    // 8 gathers in flight
            const int s0 = srt[j + 0];
            const int s1 = srt[j + 1];
            const int s2 = srt[j + 2];
            const int s3 = srt[j + 3];
            const int s4 = srt[j + 4];
            const int s5 = srt[j + 5];
            const int s6 = srt[j + 6];
            const int s7 = srt[j + 7];
            const uint2 q0 = base[(size_t)s0 * 4 + lq];
            const uint2 q1 = base[(size_t)s1 * 4 + lq];
            const uint2 q2 = base[(size_t)s2 * 4 + lq];
            const uint2 q3 = base[(size_t)s3 * 4 + lq];
            const uint2 q4 = base[(size_t)s4 * 4 + lq];
            const uint2 q5 = base[(size_t)s5 * 4 + lq];
            const uint2 q6 = base[(size_t)s6 * 4 + lq];
            const uint2 q7 = base[(size_t)s7 * 4 + lq];
            ACC8(q0); ACC8(q1); ACC8(q2); ACC8(q3);
            ACC8(q4); ACC8(q5); ACC8(q6); ACC8(q7);
        }
        for (; j + 3 < e; j += 4) {
            const int s0 = srt[j + 0];
            const int s1 = srt[j + 1];
            const int s2 = srt[j + 2];
            const int s3 = srt[j + 3];
            const uint2 q0 = base[(size_t)s0 * 4 + lq];
            const uint2 q1 = base[(size_t)s1 * 4 + lq];
            const uint2 q2 = base[(size_t)s2 * 4 + lq];
            const uint2 q3 = base[(size_t)s3 * 4 + lq];
            ACC8(q0); ACC8(q1); ACC8(q2); ACC8(q3);
        }
        for (; j < e; ++j) {
            const uint2 qq = base[(size_t)srt[j] * 4 + lq];
            ACC8(qq);
        }
        const float dv = rsqrtf(1.0f + (float)cn);
        const float4 bb0 = ((const float4*)b1)[lq * 2];
        const float4 bb1 = ((const float4*)b1)[lq * 2 + 1];
        float* hp = &hs[nnl][lq * 8];
        hp[0] = fmaxf(fmaf(a0, dv, bb0.x), 0.0f);
        hp[1] = fmaxf(fmaf(a1, dv, bb0.y), 0.0f);
        hp[2] = fmaxf(fmaf(a2, dv, bb0.z), 0.0f);
        hp[3] = fmaxf(fmaf(a3, dv, bb0.w), 0.0f);
        hp[4] = fmaxf(fmaf(a4, dv, bb1.x), 0.0f);
        hp[5] = fmaxf(fmaf(a5, dv, bb1.y), 0.0f);
        hp[6] = fmaxf(fmaf(a6, dv, bb1.z), 0.0f);
        hp[7] = fmaxf(fmaf(a7, dv, bb1.w), 0.0f);
        if (lq == 0) hs[nnl][32] = dv;
    }
    __syncthreads();                                   // B9: hs ready
    {
        const int nn2 = tid >> 2;
        const int jq = tid & 3;
        const int v2 = (b << 8) + h * 128 + nn2;
        if (v2 < N_NODES) {
            const int j0 = jq * 4;
            const float dv = hs[nn2][32];
            float s0 = 0.f, s1 = 0.f, s2 = 0.f, s3 = 0.f;
#pragma unroll
            for (int k = 0; k < H1; ++k) {
                const float hk = hs[nn2][k];
                s0 = fmaf(hk, Ws[k * H2 + j0 + 0], s0);
                s1 = fmaf(hk, Ws[k * H2 + j0 + 1], s1);
                s2 = fmaf(hk, Ws[k * H2 + j0 + 2], s2);
                s3 = fmaf(hk, Ws[k * H2 + j0 + 3], s3);
            }
            uint2 o;
            o.x = (unsigned int)f2bf(s0 * dv) | ((unsigned int)f2bf(s1 * dv) << 16);
            o.y = (unsigned int)f2bf(s2 * dv) | ((unsigned int)f2bf(s3 * dv) << 16);
            ((uint2*)u2b)[(size_t)v2 * 4 + jq] = o;
        }
    }
}

// ---------------- fused pull2 + classifier (R3 structure) --------------------

#define ACC4(Q) do { \
    a0 += bf2f((unsigned short)(Q).x); \
    a1 += bf2f((unsigned short)((Q).x >> 16)); \
    a2 += bf2f((unsigned short)(Q).y); \
    a3 += bf2f((unsigned short)((Q).y >> 16)); \
} while (0)

__global__ __launch_bounds__(256) void k_pull2f(const int* __restrict__ row_ptr,
                                                const int* __restrict__ col_idx,
                                                const float* __restrict__ dinv,
                                                const unsigned int* __restrict__ u2b,
                                                const float* __restrict__ b2,
                                                const float* __restrict__ Wc,
                                                const float* __restrict__ bc,
                                                float* __restrict__ out) {
    __shared__ float hs[P_NODES][17];
    __shared__ float Wcs[H2 * NC];  // 128
    __shared__ float bcs[NC];
    __shared__ int lidx[P_CAP];     // 12 KB
    const int tid = threadIdx.x;
    if (tid < H2 * NC) Wcs[tid] = Wc[tid];
    if (tid < NC) bcs[tid] = bc[tid];
    const int v0 = blockIdx.x * P_NODES;
    const int base_off = row_ptr[v0];
    const int range = row_ptr[v0 + P_NODES] - base_off;
    const bool ovf = (range > P_CAP);
    const int stg = ovf ? 0 : range;
    for (int j = tid; j < stg; j += 256) lidx[j] = col_idx[base_off + j];
    __syncthreads();
    const int n = tid >> 3;
    const int half = (tid >> 2) & 1;
    const int lq = tid & 3;
    const int v = v0 + n;
    const uint2* base = (const uint2*)u2b;
    float a0 = 0.f, a1 = 0.f, a2 = 0.f, a3 = 0.f;
    if (half == 0) {
        const uint2 q = base[(size_t)v * 4 + lq];
        a0 = bf2f((unsigned short)q.x); a1 = bf2f((unsigned short)(q.x >> 16));
        a2 = bf2f((unsigned short)q.y); a3 = bf2f((unsigned short)(q.y >> 16));
    }
    const int beg = row_ptr[v] - base_off;
    const int end = row_ptr[v + 1] - base_off;
    int i = beg + half;
    if (!ovf) {
        for (; i + 14 < end; i += 16) {
            const int s0 = lidx[i];
            const int s1 = lidx[i + 2];
            const int s2 = lidx[i + 4];
            const int s3 = lidx[i + 6];
            const int s4 = lidx[i + 8];
            const int s5 = lidx[i + 10];
            const int s6 = lidx[i + 12];
            const int s7 = lidx[i + 14];
            const uint2 q0 = base[(size_t)s0 * 4 + lq];
            const uint2 q1 = base[(size_t)s1 * 4 + lq];
            const uint2 q2 = base[(size_t)s2 * 4 + lq];
            const uint2 q3 = base[(size_t)s3 * 4 + lq];
            const uint2 q4 = base[(size_t)s4 * 4 + lq];
            const uint2 q5 = base[(size_t)s5 * 4 + lq];
            const uint2 q6 = base[(size_t)s6 * 4 + lq];
            const uint2 q7 = base[(size_t)s7 * 4 + lq];
            ACC4(q0); ACC4(q1); ACC4(q2); ACC4(q3);
            ACC4(q4); ACC4(q5); ACC4(q6); ACC4(q7);
        }
        for (; i + 6 < end; i += 8) {
            const int s0 = lidx[i];
            const int s1 = lidx[i + 2];
            const int s2 = lidx[i + 4];
            const int s3 = lidx[i + 6];
            const uint2 q0 = base[(size_t)s0 * 4 + lq];
            const uint2 q1 = base[(size_t)s1 * 4 + lq];
            const uint2 q2 = base[(size_t)s2 * 4 + lq];
            const uint2 q3 = base[(size_t)s3 * 4 + lq];
            ACC4(q0); ACC4(q1); ACC4(q2); ACC4(q3);
        }
        for (; i < end; i += 2) {
            const uint2 qq = base[(size_t)lidx[i] * 4 + lq];
            ACC4(qq);
        }
    } else {
        const int* gp = col_idx + base_off;
        for (; i + 14 < end; i += 16) {
            const int s0 = gp[i];
            const int s1 = gp[i + 2];
            const int s2 = gp[i + 4];
            const int s3 = gp[i + 6];
            const int s4 = gp[i + 8];
            const int s5 = gp[i + 10];
            const int s6 = gp[i + 12];
            const int s7 = gp[i + 14];
            const uint2 q0 = base[(size_t)s0 * 4 + lq];
            const uint2 q1 = base[(size_t)s1 * 4 + lq];
            const uint2 q2 = base[(size_t)s2 * 4 + lq];
            const uint2 q3 = base[(size_t)s3 * 4 + lq];
            const uint2 q4 = base[(size_t)s4 * 4 + lq];
            const uint2 q5 = base[(size_t)s5 * 4 + lq];
            const uint2 q6 = base[(size_t)s6 * 4 + lq];
            const uint2 q7 = base[(size_t)s7 * 4 + lq];
            ACC4(q0); ACC4(q1); ACC4(q2); ACC4(q3);
            ACC4(q4); ACC4(q5); ACC4(q6); ACC4(q7);
        }
        for (; i < end; i += 2) {
            const uint2 qq = base[(size_t)gp[i] * 4 + lq];
            ACC4(qq);
        }
    }
    a0 += __shfl_xor(a0, 4, 64); a1 += __shfl_xor(a1, 4, 64);
    a2 += __shfl_xor(a2, 4, 64); a3 += __shfl_xor(a3, 4, 64);
    if (half == 0) {
        const float dv = dinv[v];
        const float4 bb = ((const float4*)b2)[lq];
        float* hp = &hs[n][lq * 4];
        hp[0] = fmaxf(fmaf(a0, dv, bb.x), 0.0f);
        hp[1] = fmaxf(fmaf(a1, dv, bb.y), 0.0f);
        hp[2] = fmaxf(fmaf(a2, dv, bb.z), 0.0f);
        hp[3] = fmaxf(fmaf(a3, dv, bb.w), 0.0f);
    }
    __syncthreads();
    if (tid < P_NODES) {
        const int vv = v0 + tid;
        float lg[NC];
#pragma unroll
        for (int j = 0; j < NC; ++j) lg[j] = bcs[j];
#pragma unroll
        for (int k = 0; k < H2; ++k) {
            const float hk = hs[tid][k];
#pragma unroll
            for (int j = 0; j < NC; ++j)
                lg[j] = fmaf(hk, Wcs[k * NC + j], lg[j]);
        }
        float m = lg[0];
#pragma unroll
        for (int j = 1; j < NC; ++j) m = fmaxf(m, lg[j]);
        float s = 0.0f;
#pragma unroll
        for (int j = 0; j < NC; ++j) s += expf(lg[j] - m);
        const float lse = logf(s) + m;
        float4 o0, o1;
        o0.x = lg[0] - lse; o0.y = lg[1] - lse;
        o0.z = lg[2] - lse; o0.w = lg[3] - lse;
        o1.x = lg[4] - lse; o1.y = lg[5] - lse;
        o1.z = lg[6] - lse; o1.w = lg[7] - lse;
        float4* op = (float4*)(out + (size_t)vv * NC);
        op[0] = o0; op[1] = o1;
    }
}

// ---------------- host launch ----------------

extern "C" void kernel_launch(void* const* d_in, const int* in_sizes, int n_in,
                              void* d_out, int out_size, void* d_ws, size_t ws_size,
                              hipStream_t stream) {
    const float* x   = (const float*)d_in[0];
    const int*   ei  = (const int*)d_in[1];
    const float* W1  = (const float*)d_in[2];
    const float* b1  = (const float*)d_in[3];
    const float* W2  = (const float*)d_in[4];
    const float* b2  = (const float*)d_in[5];
    const float* Wc  = (const float*)d_in[6];
    const float* bc  = (const float*)d_in[7];
    float* out = (float*)d_out;

    // workspace layout (int units). ~39.2 MB total.
    int*   bucket_cursor = (int*)d_ws;                       // 512
    float* dinv          = (float*)(bucket_cursor + 512);    // 100000
    unsigned short* W1f  = (unsigned short*)((int*)dinv + 100000); // 4096 bf16
    int*   row_ptr       = (int*)W1f + 2048;                 // 100016 (100001 used)
    int*   col_idx       = row_ptr + 100016;                 // 3200000
    unsigned int* u1q    = (unsigned int*)(col_idx + 3200000); // 800000 dwords
    unsigned int* u2b    = u1q + 800000;                     // 800000 dwords
    int*   ebuf          = (int*)(u2b + 800000);             // NBUCK*BCAP = 4804608

    hipMemsetAsync(bucket_cursor, 0, 512 * sizeof(int), stream);
    k_bscatter<<<(N_EDGES + EPB - 1) / EPB, 512, 0, stream>>>(ei, W1, bucket_cursor, W1f, ebuf);
    k_deg   <<<NBUCK, 512, 0, stream>>>(ebuf, bucket_cursor, dinv);
    k_gemm1m<<<(N_NODES + 63) / 64, 256, 0, stream>>>(x, W1f, dinv, u1q);
    k_fuse1 <<<NBUCK * 2, 512, 0, stream>>>(ebuf, bucket_cursor, u1q, b1, W2, row_ptr, col_idx, u2b);
    k_pull2f<<<N_NODES / P_NODES, 256, 0, stream>>>(row_ptr, col_idx, dinv, u2b, b2, Wc, bc, out);
}

// Round 8
// 203.720 us; speedup vs baseline: 6.2723x; 1.0076x over previous
//
#include <hip/hip_runtime.h>
#include <math.h>

#define N_NODES 100000
#define N_EDGES 3200000
#define D_FEAT 128
#define H1 32
#define H2 16
#define NC 8

#define NBUCK 391          // buckets of 256 dst nodes: ceil(100000/256)
#define BCAP 12288         // ebuf slots per bucket (mean 8186)
#define HCAP 6144          // srt slots per half-bucket (mean 4093)
#define EPB 4096           // edges per k_bscatter block
#define EPT 8              // edges per thread (EPB / 512)

#define P_NODES 32         // nodes per pull2 block
#define P_CAP 3072         // staged col_idx slots in pull2

typedef short s16x8 __attribute__((ext_vector_type(8)));
typedef float f32x4 __attribute__((ext_vector_type(4)));

// bf16 helpers (round-to-nearest-even pack, shift-expand)
__device__ inline unsigned short f2bf(float f) {
    unsigned int u = __float_as_uint(f);
    u += 0x7FFF + ((u >> 16) & 1);
    return (unsigned short)(u >> 16);
}
__device__ inline float bf2f(unsigned short h) {
    return __uint_as_float((unsigned int)h << 16);
}

// 64-lane inclusive scan, no barriers
__device__ inline int wave_scan_incl(int v, int lane) {
#pragma unroll
    for (int off = 1; off < 64; off <<= 1) {
        const int t = __shfl_up(v, off, 64);
        if (lane >= off) v += t;
    }
    return v;
}

// ---------------- pass A: bucket scatter via block-local LDS counting sort ---
// Folds in: per-block is64 detection and (block 0 only) W1 bf16 fragment prep.
// NO per-edge global atomics (R5 lesson).

__global__ __launch_bounds__(512) void k_bscatter(const int* __restrict__ ei,
                                                  const float* __restrict__ W1,
                                                  int* __restrict__ bucket_cursor,
                                                  unsigned short* __restrict__ W1f,
                                                  int* __restrict__ ebuf) {
    __shared__ int hist[NBUCK];
    __shared__ int lofs[NBUCK];
    __shared__ int rank[NBUCK];
    __shared__ int gb[NBUCK];
    __shared__ int wsum[8];
    __shared__ int s_is64;
    __shared__ int pay[EPB];                 // 16 KB
    __shared__ unsigned short pbk[EPB];      // 8 KB
    const int tid = threadIdx.x;
    const int lane = tid & 63;
    const int wid = tid >> 6;
    for (int i = tid; i < NBUCK; i += 512) { hist[i] = 0; rank[i] = 0; }
    if (tid < 64) {                          // wave-local is64 detect (64 samples)
        int v = ei[2 * tid + 1];
#pragma unroll
        for (int off = 1; off < 64; off <<= 1) v |= __shfl_xor(v, off, 64);
        if (tid == 0) s_is64 = (v == 0) ? 1 : 0;
    }
    if (blockIdx.x == 0) {                   // W1 MFMA B-fragment prep
        for (int idx = tid; idx < 2 * 4 * 64 * 8; idx += 512) {
            const int j    = idx & 7;
            const int ln   = (idx >> 3) & 63;
            const int kk   = (idx >> 9) & 3;
            const int nt   = idx >> 11;
            const int k = kk * 32 + ((ln >> 4) << 3) + j;
            const int n = nt * 16 + (ln & 15);
            W1f[idx] = f2bf(W1[k * H1 + n]);
        }
    }
    __syncthreads();
    const int e0 = blockIdx.x * EPB;
    const int n = min(EPB, N_EDGES - e0);    // always even
    const bool is64 = (s_is64 != 0);
    int rs[EPT], rd[EPT];
    if (is64) {
#pragma unroll
        for (int k = 0; k < EPT / 2; ++k) {
            const int i = 2 * (tid + k * 512);
            if (i < n) {
                const int e = e0 + i;
                const int4 s = *(const int4*)&ei[2 * e];
                const int4 d = *(const int4*)&ei[2 * N_EDGES + 2 * e];
                rs[2 * k] = s.x; rs[2 * k + 1] = s.z;
                rd[2 * k] = d.x; rd[2 * k + 1] = d.z;
                atomicAdd(&hist[d.x >> 8], 1);
                atomicAdd(&hist[d.z >> 8], 1);
            }
        }
    } else {
#pragma unroll
        for (int k = 0; k < EPT / 2; ++k) {
            const int i = 2 * (tid + k * 512);
            if (i < n) {
                const int e = e0 + i;
                const int2 s = *(const int2*)&ei[e];
                const int2 d = *(const int2*)&ei[N_EDGES + e];
                rs[2 * k] = s.x; rs[2 * k + 1] = s.y;
                rd[2 * k] = d.x; rd[2 * k + 1] = d.y;
                atomicAdd(&hist[d.x >> 8], 1);
                atomicAdd(&hist[d.y >> 8], 1);
            }
        }
    }
    __syncthreads();
    const int own = (tid < NBUCK) ? hist[tid] : 0;
    int incl = wave_scan_incl(own, lane);
    if (lane == 63) wsum[wid] = incl;
    __syncthreads();
    if (tid == 0) {
        int r = 0;
#pragma unroll
        for (int w = 0; w < 8; ++w) { const int t = wsum[w]; wsum[w] = r; r += t; }
    }
    __syncthreads();
    incl += wsum[wid];
    if (tid < NBUCK) {
        lofs[tid] = incl - own;
        if (own > 0) gb[tid] = tid * BCAP + atomicAdd(&bucket_cursor[tid], own);
    }
    __syncthreads();
#pragma unroll
    for (int k = 0; k < EPT / 2; ++k) {
        const int i = 2 * (tid + k * 512);
        if (i < n) {
#pragma unroll
            for (int j = 0; j < 2; ++j) {
                const int b = rd[2 * k + j] >> 8;
                const int p = lofs[b] + atomicAdd(&rank[b], 1);
                pay[p] = (rs[2 * k + j] << 8) | (rd[2 * k + j] & 255);
                pbk[p] = (unsigned short)b;
            }
        }
    }
    __syncthreads();
    for (int p = tid; p < n; p += 512) {
        const int b = pbk[p];
        ebuf[gb[b] + (p - lofs[b])] = pay[p];
    }
}

// ---------------- fused degree + layer-1 MFMA --------------------------------
// One block per bucket (391 x 512). Phase 1: histogram own bucket from ebuf
// (LDS atomics) -> degc (for fuse1) + dinv (for pull2f). Phase 2: MFMA for
// the bucket's 256 rows (8 waves x 2 tiles of 16), dinv computed locally,
// fp8-packed u1q output. 100000 = 390*256+160, 160%16==0 -> tiles fully
// valid or fully invalid; no partial-tile guards needed.

__global__ __launch_bounds__(512) void k_gemm1d(const float* __restrict__ x,
                                                const unsigned short* __restrict__ W1f,
                                                const int* __restrict__ ebuf,
                                                const int* __restrict__ bucket_cursor,
                                                int* __restrict__ degc,
                                                float* __restrict__ dinv,
                                                unsigned int* __restrict__ u1q) {
    __shared__ float os[8][2][16][33];   // 33.8 KB
    __shared__ int cnt[256];
    const int b = blockIdx.x;
    const int tid = threadIdx.x;
    if (tid < 256) cnt[tid] = 0;
    __syncthreads();
    const int nb = bucket_cursor[b];
    const int rb = b * BCAP;
    for (int i = tid; i < nb; i += 512)
        atomicAdd(&cnt[ebuf[rb + i] & 255], 1);
    __syncthreads();
    if (tid < 256) {
        const int v = (b << 8) + tid;
        degc[v] = cnt[tid];
        if (v < N_NODES) dinv[v] = rsqrtf(1.0f + (float)cnt[tid]);
    }
    const int w = tid >> 6;
    const int lane = tid & 63;
    const int m = lane & 15;
    const int quad = lane >> 4;
    const s16x8* bf = (const s16x8*)W1f;
    const int tA = w * 2, tB = w * 2 + 1;
    const int rowA = (b << 8) + tA * 16;
    const int rowB = (b << 8) + tB * 16;
    const bool actA = (rowA < N_NODES);
    const bool actB = (rowB < N_NODES);
    if (actA) {
        f32x4 acc0 = {0.f, 0.f, 0.f, 0.f};
        f32x4 acc1 = {0.f, 0.f, 0.f, 0.f};
#pragma unroll
        for (int kk = 0; kk < 4; ++kk) {
            const float* xp = x + (size_t)(rowA + m) * D_FEAT + kk * 32 + quad * 8;
            const float4 p0 = ((const float4*)xp)[0];
            const float4 p1 = ((const float4*)xp)[1];
            s16x8 a;
            a[0] = (short)f2bf(p0.x); a[1] = (short)f2bf(p0.y);
            a[2] = (short)f2bf(p0.z); a[3] = (short)f2bf(p0.w);
            a[4] = (short)f2bf(p1.x); a[5] = (short)f2bf(p1.y);
            a[6] = (short)f2bf(p1.z); a[7] = (short)f2bf(p1.w);
            acc0 = __builtin_amdgcn_mfma_f32_16x16x32_bf16(a, bf[kk * 64 + lane], acc0, 0, 0, 0);
            acc1 = __builtin_amdgcn_mfma_f32_16x16x32_bf16(a, bf[(4 + kk) * 64 + lane], acc1, 0, 0, 0);
        }
#pragma unroll
        for (int r = 0; r < 4; ++r) {
            os[w][0][quad * 4 + r][m]      = acc0[r];
            os[w][0][quad * 4 + r][16 + m] = acc1[r];
        }
    }
    if (actB) {
        f32x4 acc0 = {0.f, 0.f, 0.f, 0.f};
        f32x4 acc1 = {0.f, 0.f, 0.f, 0.f};
#pragma unroll
        for (int kk = 0; kk < 4; ++kk) {
            const float* xp = x + (size_t)(rowB + m) * D_FEAT + kk * 32 + quad * 8;
            const float4 p0 = ((const float4*)xp)[0];
            const float4 p1 = ((const float4*)xp)[1];
            s16x8 a;
            a[0] = (short)f2bf(p0.x); a[1] = (short)f2bf(p0.y);
            a[2] = (short)f2bf(p0.z); a[3] = (short)f2bf(p0.w);
            a[4] = (short)f2bf(p1.x); a[5] = (short)f2bf(p1.y);
            a[6] = (short)f2bf(p1.z); a[7] = (short)f2bf(p1.w);
            acc0 = __builtin_amdgcn_mfma_f32_16x16x32_bf16(a, bf[kk * 64 + lane], acc0, 0, 0, 0);
            acc1 = __builtin_amdgcn_mfma_f32_16x16x32_bf16(a, bf[(4 + kk) * 64 + lane], acc1, 0, 0, 0);
        }
#pragma unroll
        for (int r = 0; r < 4; ++r) {
            os[w][1][quad * 4 + r][m]      = acc0[r];
            os[w][1][quad * 4 + r][16 + m] = acc1[r];
        }
    }
    __syncthreads();
    const int rl = lane >> 2;       // row-in-tile 0..15
    const int seg = lane & 3;       // 8-col segment
    if (actA) {
        const int row = rowA + rl;
        const float dv = rsqrtf(1.0f + (float)cnt[tA * 16 + rl]);
        const float* p = &os[w][0][rl][seg * 8];
        unsigned int pk0 = __builtin_amdgcn_cvt_pk_fp8_f32(p[0] * dv, p[1] * dv, 0u, false);
        pk0 = __builtin_amdgcn_cvt_pk_fp8_f32(p[2] * dv, p[3] * dv, pk0, true);
        unsigned int pk1 = __builtin_amdgcn_cvt_pk_fp8_f32(p[4] * dv, p[5] * dv, 0u, false);
        pk1 = __builtin_amdgcn_cvt_pk_fp8_f32(p[6] * dv, p[7] * dv, pk1, true);
        uint2 o; o.x = pk0; o.y = pk1;
        ((uint2*)u1q)[(size_t)row * 4 + seg] = o;
    }
    if (actB) {
        const int row = rowB + rl;
        const float dv = rsqrtf(1.0f + (float)cnt[tB * 16 + rl]);
        const float* p = &os[w][1][rl][seg * 8];
        unsigned int pk0 = __builtin_amdgcn_cvt_pk_fp8_f32(p[0] * dv, p[1] * dv, 0u, false);
        pk0 = __builtin_amdgcn_cvt_pk_fp8_f32(p[2] * dv, p[3] * dv, pk0, true);
        unsigned int pk1 = __builtin_amdgcn_cvt_pk_fp8_f32(p[4] * dv, p[5] * dv, 0u, false);
        pk1 = __builtin_amdgcn_cvt_pk_fp8_f32(p[6] * dv, p[7] * dv, pk1, true);
        uint2 o; o.x = pk0; o.y = pk1;
        ((uint2*)u1q)[(size_t)row * 4 + seg] = o;
    }
}

// ---------------- fused sort + pull1 + GEMM2 ---------------------------------
// Histogram phase removed (R8): cnt comes from degc (written by k_gemm1d).
// ebuf is read ONCE (scatter pass). Rest identical to R5/R7 structure.

#define ACC8(Q) do { \
    a0 += __builtin_amdgcn_cvt_f32_fp8((Q).x, 0); \
    a1 += __builtin_amdgcn_cvt_f32_fp8((Q).x, 1); \
    a2 += __builtin_amdgcn_cvt_f32_fp8((Q).x, 2); \
    a3 += __builtin_amdgcn_cvt_f32_fp8((Q).x, 3); \
    a4 += __builtin_amdgcn_cvt_f32_fp8((Q).y, 0); \
    a5 += __builtin_amdgcn_cvt_f32_fp8((Q).y, 1); \
    a6 += __builtin_amdgcn_cvt_f32_fp8((Q).y, 2); \
    a7 += __builtin_amdgcn_cvt_f32_fp8((Q).y, 3); \
} while (0)

__global__ __launch_bounds__(512) void k_fuse1(const int* __restrict__ ebuf,
                                               const int* __restrict__ bucket_cursor,
                                               const int* __restrict__ degc,
                                               const unsigned int* __restrict__ u1q,
                                               const float* __restrict__ b1,
                                               const float* __restrict__ W2,
                                               int* __restrict__ row_ptr,
                                               int* __restrict__ col_idx,
                                               unsigned int* __restrict__ u2b) {
    __shared__ int srt[HCAP];       // 24 KB sorted src of own half
    __shared__ int cnt[256];
    __shared__ int cur[256];
    __shared__ int wsum[8];
    __shared__ int wsum2[4];
    __shared__ float Ws[H1 * H2];   // 2 KB
    __shared__ float hs[128][33];   // 16.9 KB
    __shared__ int s_wb, s_base, s_nh;
    const int b = blockIdx.x >> 1;
    const int h = blockIdx.x & 1;
    const int tid = threadIdx.x;
    const int lane = tid & 63;
    const int wid = tid >> 6;
    if (tid < 256) cnt[tid] = degc[(b << 8) + tid];   // degrees from gemm1d
    for (int i = tid; i < H1 * H2; i += 512) Ws[i] = W2[i];
    // cross-bucket exclusive scan of final bucket counts -> wb
    const int own0 = (tid < NBUCK) ? bucket_cursor[tid] : 0;
    int incl0 = wave_scan_incl(own0, lane);
    if (lane == 63) wsum[wid] = incl0;
    __syncthreads();                                   // B1
    if (tid == 0) {
        int r = 0;
#pragma unroll
        for (int w = 0; w < 8; ++w) { const int t = wsum[w]; wsum[w] = r; r += t; }
    }
    __syncthreads();                                   // B2
    if (tid == b) s_wb = incl0 + wsum[wid] - own0;
    const int nb = bucket_cursor[b];
    const int rb = b * BCAP;
    // 256-wide scan of cnt (own value -> register, cross-thread via barriers)
    int ownc = 0, inclc = 0;
    if (tid < 256) {
        ownc = cnt[tid];
        inclc = wave_scan_incl(ownc, lane);
        if (lane == 63) wsum2[wid] = inclc;
    }
    __syncthreads();                                   // B4
    if (tid == 0) {
        int r = 0;
#pragma unroll
        for (int w = 0; w < 4; ++w) { const int t = wsum2[w]; wsum2[w] = r; r += t; }
    }
    __syncthreads();                                   // B5
    const int wb = s_wb;
    if (tid < 256) {
        inclc += wsum2[wid];
        const int excl = inclc - ownc;
        cur[tid] = excl;
        const int v = (b << 8) + tid;
        if (v <= N_NODES) row_ptr[v] = wb + excl;      // covers row_ptr[N_NODES]
    }
    __syncthreads();                                   // B6: cur=excl ready
    if (tid == 0) {
        s_base = cur[h * 128];                         // half's first global slot
        s_nh = (h ? nb : cur[128]) - cur[h * 128];     // edges in this half
    }
    __syncthreads();                                   // B7
    const int base_h = s_base;
    const int nh = s_nh;
    // scatter own half's edges into srt (local slots), sorted by dst
    for (int i = tid; i < nb; i += 512) {
        const int pk = ebuf[rb + i];
        const int dl = pk & 255;
        if ((dl >> 7) == h) {
            const int slot = atomicAdd(&cur[dl], 1);
            srt[slot - base_h] = pk >> 8;
        }
    }
    __syncthreads();                                   // B8: srt ready, cur=incl
    // coalesced col_idx write for pull2
    for (int i = tid; i < nh; i += 512)
        col_idx[wb + base_h + i] = srt[i];
    // per-node register gather (4 lanes/node, 8-deep pipeline)
    const int nnl = tid >> 2;       // node-in-half 0..127
    const int lq = tid & 3;         // feature lane (8 fp8 = 8B each)
    const int nn = h * 128 + nnl;
    const int v = (b << 8) + nn;
    if (v < N_NODES) {
        const uint2* base = (const uint2*)u1q;
        const uint2 q = base[(size_t)v * 4 + lq];      // self-loop term
        float a0 = __builtin_amdgcn_cvt_f32_fp8(q.x, 0);
        float a1 = __builtin_amdgcn_cvt_f32_fp8(q.x, 1);
        float a2 = __builtin_amdgcn_cvt_f32_fp8(q.x, 2);
        float a3 = __builtin_amdgcn_cvt_f32_fp8(q.x, 3);
        float a4 = __builtin_amdgcn_cvt_f32_fp8(q.y, 0);
        float a5 = __builtin_amdgcn_cvt_f32_fp8(q.y, 1);
        float a6 = __builtin_amdgcn_cvt_f32_fp8(q.y, 2);
        float a7 = __builtin_amdgcn_cvt_f32_fp8(q.y, 3);
        const int cn = cnt[nn];
        const int e = cur[nn] - base_h;                // local end
        int j = e - cn;                                // local start
        for (; j + 7 < e; j += 8) {                    // 8 gathers in flight
            const int s0 = srt[j + 0];
            const int s1 = srt[j + 1];
            const int s2 = srt[j + 2];
            const int s3 = srt[j + 3];
            const int s4 = srt[j + 4];
            const int s5 = srt[j + 5];
            const int s6 = srt[j + 6];
            const int s7 = srt[j + 7];
            const uint2 q0 = base[(size_t)s0 * 4 + lq];
            const uint2 q1 = base[(size_t)s1 * 4 + lq];
            const uint2 q2 = base[(size_t)s2 * 4 + lq];
            const uint2 q3 = base[(size_t)s3 * 4 + lq];
            const uint2 q4 = base[(size_t)s4 * 4 + lq];
            const uint2 q5 = base[(size_t)s5 * 4 + lq];
            const uint2 q6 = base[(size_t)s6 * 4 + lq];
            const uint2 q7 = base[(size_t)s7 * 4 + lq];
            ACC8(q0); ACC8(q1); ACC8(q2); ACC8(q3);
            ACC8(q4); ACC8(q5); ACC8(q6); ACC8(q7);
        }
        for (; j + 3 < e; j += 4) {
            const int s0 = srt[j + 0];
            const int s1 = srt[j + 1];
            const int s2 = srt[j + 2];
            const int s3 = srt[j + 3];
            const uint2 q0 = base[(size_t)s0 * 4 + lq];
            const uint2 q1 = base[(size_t)s1 * 4 + lq];
            const uint2 q2 = base[(size_t)s2 * 4 + lq];
            const uint2 q3 = base[(size_t)s3 * 4 + lq];
            ACC8(q0); ACC8(q1); ACC8(q2); ACC8(q3);
        }
        for (; j < e; ++j) {
            const uint2 qq = base[(size_t)srt[j] * 4 + lq];
            ACC8(qq);
        }
        const float dv = rsqrtf(1.0f + (float)cn);
        const float4 bb0 = ((const float4*)b1)[lq * 2];
        const float4 bb1 = ((const float4*)b1)[lq * 2 + 1];
        float* hp = &hs[nnl][lq * 8];
        hp[0] = fmaxf(fmaf(a0, dv, bb0.x), 0.0f);
        hp[1] = fmaxf(fmaf(a1, dv, bb0.y), 0.0f);
        hp[2] = fmaxf(fmaf(a2, dv, bb0.z), 0.0f);
        hp[3] = fmaxf(fmaf(a3, dv, bb0.w), 0.0f);
        hp[4] = fmaxf(fmaf(a4, dv, bb1.x), 0.0f);
        hp[5] = fmaxf(fmaf(a5, dv, bb1.y), 0.0f);
        hp[6] = fmaxf(fmaf(a6, dv, bb1.z), 0.0f);
        hp[7] = fmaxf(fmaf(a7, dv, bb1.w), 0.0f);
        if (lq == 0) hs[nnl][32] = dv;
    }
    __syncthreads();                                   // B9: hs ready
    {
        const int nn2 = tid >> 2;
        const int jq = tid & 3;
        const int v2 = (b << 8) + h * 128 + nn2;
        if (v2 < N_NODES) {
            const int j0 = jq * 4;
            const float dv = hs[nn2][32];
            float s0 = 0.f, s1 = 0.f, s2 = 0.f, s3 = 0.f;
#pragma unroll
            for (int k = 0; k < H1; ++k) {
                const float hk = hs[nn2][k];
                s0 = fmaf(hk, Ws[k * H2 + j0 + 0], s0);
                s1 = fmaf(hk, Ws[k * H2 + j0 + 1], s1);
                s2 = fmaf(hk, Ws[k * H2 + j0 + 2], s2);
                s3 = fmaf(hk, Ws[k * H2 + j0 + 3], s3);
            }
            uint2 o;
            o.x = (unsigned int)f2bf(s0 * dv) | ((unsigned int)f2bf(s1 * dv) << 16);
            o.y = (unsigned int)f2bf(s2 * dv) | ((unsigned int)f2bf(s3 * dv) << 16);
            ((uint2*)u2b)[(size_t)v2 * 4 + jq] = o;
        }
    }
}

// ---------------- fused pull2 + classifier (unchanged) -----------------------

#define ACC4(Q) do { \
    a0 += bf2f((unsigned short)(Q).x); \
    a1 += bf2f((unsigned short)((Q).x >> 16)); \
    a2 += bf2f((unsigned short)(Q).y); \
    a3 += bf2f((unsigned short)((Q).y >> 16)); \
} while (0)

__global__ __launch_bounds__(256) void k_pull2f(const int* __restrict__ row_ptr,
                                                const int* __restrict__ col_idx,
                                                const float* __restrict__ dinv,
                                                const unsigned int* __restrict__ u2b,
                                                const float* __restrict__ b2,
                                                const float* __restrict__ Wc,
                                                const float* __restrict__ bc,
                                                float* __restrict__ out) {
    __shared__ float hs[P_NODES][17];
    __shared__ float Wcs[H2 * NC];  // 128
    __shared__ float bcs[NC];
    __shared__ int lidx[P_CAP];     // 12 KB
    const int tid = threadIdx.x;
    if (tid < H2 * NC) Wcs[tid] = Wc[tid];
    if (tid < NC) bcs[tid] = bc[tid];
    const int v0 = blockIdx.x * P_NODES;
    const int base_off = row_ptr[v0];
    const int range = row_ptr[v0 + P_NODES] - base_off;
    const bool ovf = (range > P_CAP);
    const int stg = ovf ? 0 : range;
    for (int j = tid; j < stg; j += 256) lidx[j] = col_idx[base_off + j];
    __syncthreads();
    const int n = tid >> 3;
    const int half = (tid >> 2) & 1;
    const int lq = tid & 3;
    const int v = v0 + n;
    const uint2* base = (const uint2*)u2b;
    float a0 = 0.f, a1 = 0.f, a2 = 0.f, a3 = 0.f;
    if (half == 0) {
        const uint2 q = base[(size_t)v * 4 + lq];
        a0 = bf2f((unsigned short)q.x); a1 = bf2f((unsigned short)(q.x >> 16));
        a2 = bf2f((unsigned short)q.y); a3 = bf2f((unsigned short)(q.y >> 16));
    }
    const int beg = row_ptr[v] - base_off;
    const int end = row_ptr[v + 1] - base_off;
    int i = beg + half;
    if (!ovf) {
        for (; i + 14 < end; i += 16) {
            const int s0 = lidx[i];
            const int s1 = lidx[i + 2];
            const int s2 = lidx[i + 4];
            const int s3 = lidx[i + 6];
            const int s4 = lidx[i + 8];
            const int s5 = lidx[i + 10];
            const int s6 = lidx[i + 12];
            const int s7 = lidx[i + 14];
            const uint2 q0 = base[(size_t)s0 * 4 + lq];
            const uint2 q1 = base[(size_t)s1 * 4 + lq];
            const uint2 q2 = base[(size_t)s2 * 4 + lq];
            const uint2 q3 = base[(size_t)s3 * 4 + lq];
            const uint2 q4 = base[(size_t)s4 * 4 + lq];
            const uint2 q5 = base[(size_t)s5 * 4 + lq];
            const uint2 q6 = base[(size_t)s6 * 4 + lq];
            const uint2 q7 = base[(size_t)s7 * 4 + lq];
            ACC4(q0); ACC4(q1); ACC4(q2); ACC4(q3);
            ACC4(q4); ACC4(q5); ACC4(q6); ACC4(q7);
        }
        for (; i + 6 < end; i += 8) {
            const int s0 = lidx[i];
            const int s1 = lidx[i + 2];
            const int s2 = lidx[i + 4];
            const int s3 = lidx[i + 6];
            const uint2 q0 = base[(size_t)s0 * 4 + lq];
            const uint2 q1 = base[(size_t)s1 * 4 + lq];
            const uint2 q2 = base[(size_t)s2 * 4 + lq];
            const uint2 q3 = base[(size_t)s3 * 4 + lq];
            ACC4(q0); ACC4(q1); ACC4(q2); ACC4(q3);
        }
        for (; i < end; i += 2) {
            const uint2 qq = base[(size_t)lidx[i] * 4 + lq];
            ACC4(qq);
        }
    } else {
        const int* gp = col_idx + base_off;
        for (; i + 14 < end; i += 16) {
            const int s0 = gp[i];
            const int s1 = gp[i + 2];
            const int s2 = gp[i + 4];
            const int s3 = gp[i + 6];
            const int s4 = gp[i + 8];
            const int s5 = gp[i + 10];
            const int s6 = gp[i + 12];
            const int s7 = gp[i + 14];
            const uint2 q0 = base[(size_t)s0 * 4 + lq];
            const uint2 q1 = base[(size_t)s1 * 4 + lq];
            const uint2 q2 = base[(size_t)s2 * 4 + lq];
            const uint2 q3 = base[(size_t)s3 * 4 + lq];
            const uint2 q4 = base[(size_t)s4 * 4 + lq];
            const uint2 q5 = base[(size_t)s5 * 4 + lq];
            const uint2 q6 = base[(size_t)s6 * 4 + lq];
            const uint2 q7 = base[(size_t)s7 * 4 + lq];
            ACC4(q0); ACC4(q1); ACC4(q2); ACC4(q3);
            ACC4(q4); ACC4(q5); ACC4(q6); ACC4(q7);
        }
        for (; i < end; i += 2) {
            const uint2 qq = base[(size_t)gp[i] * 4 + lq];
            ACC4(qq);
        }
    }
    a0 += __shfl_xor(a0, 4, 64); a1 += __shfl_xor(a1, 4, 64);
    a2 += __shfl_xor(a2, 4, 64); a3 += __shfl_xor(a3, 4, 64);
    if (half == 0) {
        const float dv = dinv[v];
        const float4 bb = ((const float4*)b2)[lq];
        float* hp = &hs[n][lq * 4];
        hp[0] = fmaxf(fmaf(a0, dv, bb.x), 0.0f);
        hp[1] = fmaxf(fmaf(a1, dv, bb.y), 0.0f);
        hp[2] = fmaxf(fmaf(a2, dv, bb.z), 0.0f);
        hp[3] = fmaxf(fmaf(a3, dv, bb.w), 0.0f);
    }
    __syncthreads();
    if (tid < P_NODES) {
        const int vv = v0 + tid;
        float lg[NC];
#pragma unroll
        for (int j = 0; j < NC; ++j) lg[j] = bcs[j];
#pragma unroll
        for (int k = 0; k < H2; ++k) {
            const float hk = hs[tid][k];
#pragma unroll
            for (int j = 0; j < NC; ++j)
                lg[j] = fmaf(hk, Wcs[k * NC + j], lg[j]);
        }
        float m = lg[0];
#pragma unroll
        for (int j = 1; j < NC; ++j) m = fmaxf(m, lg[j]);
        float s = 0.0f;
#pragma unroll
        for (int j = 0; j < NC; ++j) s += expf(lg[j] - m);
        const float lse = logf(s) + m;
        float4 o0, o1;
        o0.x = lg[0] - lse; o0.y = lg[1] - lse;
        o0.z = lg[2] - lse; o0.w = lg[3] - lse;
        o1.x = lg[4] - lse; o1.y = lg[5] - lse;
        o1.z = lg[6] - lse; o1.w = lg[7] - lse;
        float4* op = (float4*)(out + (size_t)vv * NC);
        op[0] = o0; op[1] = o1;
    }
}

// ---------------- host launch ----------------

extern "C" void kernel_launch(void* const* d_in, const int* in_sizes, int n_in,
                              void* d_out, int out_size, void* d_ws, size_t ws_size,
                              hipStream_t stream) {
    const float* x   = (const float*)d_in[0];
    const int*   ei  = (const int*)d_in[1];
    const float* W1  = (const float*)d_in[2];
    const float* b1  = (const float*)d_in[3];
    const float* W2  = (const float*)d_in[4];
    const float* b2  = (const float*)d_in[5];
    const float* Wc  = (const float*)d_in[6];
    const float* bc  = (const float*)d_in[7];
    float* out = (float*)d_out;

    // workspace layout (int units). ~39.6 MB total.
    int*   bucket_cursor = (int*)d_ws;                       // 512
    float* dinv          = (float*)(bucket_cursor + 512);    // 100000
    int*   degc          = (int*)dinv + 100000;              // 100096
    unsigned short* W1f  = (unsigned short*)(degc + 100096); // 4096 bf16
    int*   row_ptr       = (int*)W1f + 2048;                 // 100016 (100001 used)
    int*   col_idx       = row_ptr + 100016;                 // 3200000
    unsigned int* u1q    = (unsigned int*)(col_idx + 3200000); // 800000 dwords
    unsigned int* u2b    = u1q + 800000;                     // 800000 dwords
    int*   ebuf          = (int*)(u2b + 800000);             // NBUCK*BCAP = 4804608

    hipMemsetAsync(bucket_cursor, 0, 512 * sizeof(int), stream);
    k_bscatter<<<(N_EDGES + EPB - 1) / EPB, 512, 0, stream>>>(ei, W1, bucket_cursor, W1f, ebuf);
    k_gemm1d<<<NBUCK, 512, 0, stream>>>(x, W1f, ebuf, bucket_cursor, degc, dinv, u1q);
    k_fuse1 <<<NBUCK * 2, 512, 0, stream>>>(ebuf, bucket_cursor, degc, u1q, b1, W2, row_ptr, col_idx, u2b);
    k_pull2f<<<N_NODES / P_NODES, 256, 0, stream>>>(row_ptr, col_idx, dinv, u2b, b2, Wc, bc, out);
}

// Round 9
// 201.934 us; speedup vs baseline: 6.3278x; 1.0088x over previous
//
#include <hip/hip_runtime.h>
#include <math.h>

#define N_NODES 100000
#define N_EDGES 3200000
#define D_FEAT 128
#define H1 32
#define H2 16
#define NC 8

#define NBUCK 391          // buckets of 256 dst nodes: ceil(100000/256)
#define BCAP 12288         // ebuf slots per bucket (mean 8186)
#define HCAP 6144          // srt slots per half-bucket (mean 4093)
#define EPB 4096           // edges per scatter block
#define EPT 8              // edges per thread (EPB / 512)
#define NSB ((N_EDGES + EPB - 1) / EPB)   // 782 scatter blocks

#define P_NODES 32         // nodes per pull2 block
#define P_CAP 3072         // staged col_idx slots in pull2

typedef short s16x8 __attribute__((ext_vector_type(8)));
typedef float f32x4 __attribute__((ext_vector_type(4)));

// bf16 helpers (round-to-nearest-even pack, shift-expand)
__device__ inline unsigned short f2bf(float f) {
    unsigned int u = __float_as_uint(f);
    u += 0x7FFF + ((u >> 16) & 1);
    return (unsigned short)(u >> 16);
}
__device__ inline float bf2f(unsigned short h) {
    return __uint_as_float((unsigned int)h << 16);
}

// 64-lane inclusive scan, no barriers
__device__ inline int wave_scan_incl(int v, int lane) {
#pragma unroll
    for (int off = 1; off < 64; off <<= 1) {
        const int t = __shfl_up(v, off, 64);
        if (lane >= off) v += t;
    }
    return v;
}

// ---------------- k_pre: scatter blocks [0,NSB) + gemm blocks [NSB,NSB+NBUCK)
// Scatter: R8's bucket counting sort (LDS-pipe-bound). Gemm: y16 = bf16(x@W1)
// UNSCALED (no degree dependency) -> MFMA/VMEM-bound. Complementary pipes
// co-resident on each CU (m114: co-scheduling ~ max, not sum).

__global__ __launch_bounds__(512) void k_pre(const int* __restrict__ ei,
                                             const float* __restrict__ x,
                                             const float* __restrict__ W1,
                                             int* __restrict__ bucket_cursor,
                                             int* __restrict__ ebuf,
                                             unsigned short* __restrict__ y16) {
    __shared__ union {
        struct {
            int hist[NBUCK], lofs[NBUCK], rank[NBUCK], gb[NBUCK], wsum[8], is64;
            int pay[EPB];                // 16 KB
            unsigned short pbk[EPB];     // 8 KB
        } sc;                            // ~30.1 KB
        struct {
            unsigned short wf[2 * 4 * 64 * 8];  // 8 KB W1 fragments
            float os[8][16][33];                // 16.9 KB per-wave staging
        } gm;                            // ~25 KB
    } u;
    const int tid = threadIdx.x;
    const int lane = tid & 63;
    const int wid = tid >> 6;

    if (blockIdx.x >= NSB) {
        // ---------------- gemm path ----------------
        const int gb_ = blockIdx.x - NSB;
        for (int idx = tid; idx < 2 * 4 * 64 * 8; idx += 512) {
            const int j  = idx & 7;
            const int ln = (idx >> 3) & 63;
            const int kk = (idx >> 9) & 3;
            const int nt = idx >> 11;
            const int k = kk * 32 + ((ln >> 4) << 3) + j;
            const int n = nt * 16 + (ln & 15);
            u.gm.wf[idx] = f2bf(W1[k * H1 + n]);
        }
        __syncthreads();
        const int w = tid >> 6;
        const int m = lane & 15;
        const int quad = lane >> 4;
        const int rl = lane >> 2;
        const int seg = lane & 3;
        const s16x8* bf = (const s16x8*)u.gm.wf;
#pragma unroll
        for (int t = 0; t < 2; ++t) {
            const int row0 = (gb_ << 8) + (w * 2 + t) * 16;
            const bool act = (row0 < N_NODES);   // 160 % 16 == 0: full tiles
            if (act) {
                f32x4 acc0 = {0.f, 0.f, 0.f, 0.f};
                f32x4 acc1 = {0.f, 0.f, 0.f, 0.f};
#pragma unroll
                for (int kk = 0; kk < 4; ++kk) {
                    const float* xp = x + (size_t)(row0 + m) * D_FEAT + kk * 32 + quad * 8;
                    const float4 p0 = ((const float4*)xp)[0];
                    const float4 p1 = ((const float4*)xp)[1];
                    s16x8 a;
                    a[0] = (short)f2bf(p0.x); a[1] = (short)f2bf(p0.y);
                    a[2] = (short)f2bf(p0.z); a[3] = (short)f2bf(p0.w);
                    a[4] = (short)f2bf(p1.x); a[5] = (short)f2bf(p1.y);
                    a[6] = (short)f2bf(p1.z); a[7] = (short)f2bf(p1.w);
                    acc0 = __builtin_amdgcn_mfma_f32_16x16x32_bf16(a, bf[kk * 64 + lane], acc0, 0, 0, 0);
                    acc1 = __builtin_amdgcn_mfma_f32_16x16x32_bf16(a, bf[(4 + kk) * 64 + lane], acc1, 0, 0, 0);
                }
#pragma unroll
                for (int r = 0; r < 4; ++r) {
                    u.gm.os[w][quad * 4 + r][m]      = acc0[r];
                    u.gm.os[w][quad * 4 + r][16 + m] = acc1[r];
                }
            }
            __syncthreads();
            if (act) {
                const int row = row0 + rl;
                const float* p = &u.gm.os[w][rl][seg * 8];
                uint4 o;
                o.x = (unsigned int)f2bf(p[0]) | ((unsigned int)f2bf(p[1]) << 16);
                o.y = (unsigned int)f2bf(p[2]) | ((unsigned int)f2bf(p[3]) << 16);
                o.z = (unsigned int)f2bf(p[4]) | ((unsigned int)f2bf(p[5]) << 16);
                o.w = (unsigned int)f2bf(p[6]) | ((unsigned int)f2bf(p[7]) << 16);
                *(uint4*)(y16 + (size_t)row * 32 + seg * 8) = o;
            }
            __syncthreads();
        }
        return;
    }

    // ---------------- scatter path (R8 k_bscatter) ----------------
    for (int i = tid; i < NBUCK; i += 512) { u.sc.hist[i] = 0; u.sc.rank[i] = 0; }
    if (tid < 64) {                          // wave-local is64 detect
        int v = ei[2 * tid + 1];
#pragma unroll
        for (int off = 1; off < 64; off <<= 1) v |= __shfl_xor(v, off, 64);
        if (tid == 0) u.sc.is64 = (v == 0) ? 1 : 0;
    }
    __syncthreads();
    const int e0 = blockIdx.x * EPB;
    const int n = min(EPB, N_EDGES - e0);    // always even
    const bool is64 = (u.sc.is64 != 0);
    int rs[EPT], rd[EPT];
    if (is64) {
#pragma unroll
        for (int k = 0; k < EPT / 2; ++k) {
            const int i = 2 * (tid + k * 512);
            if (i < n) {
                const int e = e0 + i;
                const int4 s = *(const int4*)&ei[2 * e];
                const int4 d = *(const int4*)&ei[2 * N_EDGES + 2 * e];
                rs[2 * k] = s.x; rs[2 * k + 1] = s.z;
                rd[2 * k] = d.x; rd[2 * k + 1] = d.z;
                atomicAdd(&u.sc.hist[d.x >> 8], 1);
                atomicAdd(&u.sc.hist[d.z >> 8], 1);
            }
        }
    } else {
#pragma unroll
        for (int k = 0; k < EPT / 2; ++k) {
            const int i = 2 * (tid + k * 512);
            if (i < n) {
                const int e = e0 + i;
                const int2 s = *(const int2*)&ei[e];
                const int2 d = *(const int2*)&ei[N_EDGES + e];
                rs[2 * k] = s.x; rs[2 * k + 1] = s.y;
                rd[2 * k] = d.x; rd[2 * k + 1] = d.y;
                atomicAdd(&u.sc.hist[d.x >> 8], 1);
                atomicAdd(&u.sc.hist[d.y >> 8], 1);
            }
        }
    }
    __syncthreads();
    const int own = (tid < NBUCK) ? u.sc.hist[tid] : 0;
    int incl = wave_scan_incl(own, lane);
    if (lane == 63) u.sc.wsum[wid] = incl;
    __syncthreads();
    if (tid == 0) {
        int r = 0;
#pragma unroll
        for (int w = 0; w < 8; ++w) { const int t = u.sc.wsum[w]; u.sc.wsum[w] = r; r += t; }
    }
    __syncthreads();
    incl += u.sc.wsum[wid];
    if (tid < NBUCK) {
        u.sc.lofs[tid] = incl - own;
        if (own > 0) u.sc.gb[tid] = tid * BCAP + atomicAdd(&bucket_cursor[tid], own);
    }
    __syncthreads();
#pragma unroll
    for (int k = 0; k < EPT / 2; ++k) {
        const int i = 2 * (tid + k * 512);
        if (i < n) {
#pragma unroll
            for (int j = 0; j < 2; ++j) {
                const int b = rd[2 * k + j] >> 8;
                const int p = u.sc.lofs[b] + atomicAdd(&u.sc.rank[b], 1);
                u.sc.pay[p] = (rs[2 * k + j] << 8) | (rd[2 * k + j] & 255);
                u.sc.pbk[p] = (unsigned short)b;
            }
        }
    }
    __syncthreads();
    for (int p = tid; p < n; p += 512) {
        const int b = u.sc.pbk[p];
        ebuf[u.sc.gb[b] + (p - u.sc.lofs[b])] = u.sc.pay[p];
    }
}

// ---------------- k_mid: degree histogram + dinv-scale + fp8 pack ------------
// 391 blocks x 512. Phase 1: LDS histogram of own bucket (proven pattern).
// Phase 2: read y16 rows coalesced, scale by locally-computed dinv, pack fp8.

__global__ __launch_bounds__(512) void k_mid(const int* __restrict__ ebuf,
                                             const int* __restrict__ bucket_cursor,
                                             const unsigned short* __restrict__ y16,
                                             int* __restrict__ degc,
                                             float* __restrict__ dinv,
                                             unsigned int* __restrict__ u1q) {
    __shared__ int cnt[256];
    const int b = blockIdx.x;
    const int tid = threadIdx.x;
    if (tid < 256) cnt[tid] = 0;
    __syncthreads();
    const int nb = bucket_cursor[b];
    const int rb = b * BCAP;
    for (int i = tid; i < nb; i += 512)
        atomicAdd(&cnt[ebuf[rb + i] & 255], 1);
    __syncthreads();
    if (tid < 256) {
        const int v = (b << 8) + tid;
        const int cn = cnt[tid];
        degc[v] = cn;
        if (v < N_NODES) {
            const float dv = rsqrtf(1.0f + (float)cn);
            dinv[v] = dv;
            unsigned int r[16];
            const uint4* yp = (const uint4*)(y16 + (size_t)v * 32);
            *(uint4*)&r[0]  = yp[0];
            *(uint4*)&r[4]  = yp[1];
            *(uint4*)&r[8]  = yp[2];
            *(uint4*)&r[12] = yp[3];
            unsigned int wq[8];
#pragma unroll
            for (int j = 0; j < 8; ++j) {
                const float c0 = bf2f((unsigned short)r[2 * j]) * dv;
                const float c1 = bf2f((unsigned short)(r[2 * j] >> 16)) * dv;
                const float c2 = bf2f((unsigned short)r[2 * j + 1]) * dv;
                const float c3 = bf2f((unsigned short)(r[2 * j + 1] >> 16)) * dv;
                unsigned int pk = __builtin_amdgcn_cvt_pk_fp8_f32(c0, c1, 0u, false);
                wq[j] = __builtin_amdgcn_cvt_pk_fp8_f32(c2, c3, pk, true);
            }
            uint4 oa; oa.x = wq[0]; oa.y = wq[1]; oa.z = wq[2]; oa.w = wq[3];
            uint4 ob; ob.x = wq[4]; ob.y = wq[5]; ob.z = wq[6]; ob.w = wq[7];
            ((uint4*)u1q)[(size_t)v * 2]     = oa;
            ((uint4*)u1q)[(size_t)v * 2 + 1] = ob;
        }
    }
}

// ---------------- fused sort + pull1 + GEMM2 (unchanged from R8) -------------

#define ACC8(Q) do { \
    a0 += __builtin_amdgcn_cvt_f32_fp8((Q).x, 0); \
    a1 += __builtin_amdgcn_cvt_f32_fp8((Q).x, 1); \
    a2 += __builtin_amdgcn_cvt_f32_fp8((Q).x, 2); \
    a3 += __builtin_amdgcn_cvt_f32_fp8((Q).x, 3); \
    a4 += __builtin_amdgcn_cvt_f32_fp8((Q).y, 0); \
    a5 += __builtin_amdgcn_cvt_f32_fp8((Q).y, 1); \
    a6 += __builtin_amdgcn_cvt_f32_fp8((Q).y, 2); \
    a7 += __builtin_amdgcn_cvt_f32_fp8((Q).y, 3); \
} while (0)

__global__ __launch_bounds__(512) void k_fuse1(const int* __restrict__ ebuf,
                                               const int* __restrict__ bucket_cursor,
                                               const int* __restrict__ degc,
                                               const unsigned int* __restrict__ u1q,
                                               const float* __restrict__ b1,
                                               const float* __restrict__ W2,
                                               int* __restrict__ row_ptr,
                                               int* __restrict__ col_idx,
                                               unsigned int* __restrict__ u2b) {
    __shared__ int srt[HCAP];       // 24 KB sorted src of own half
    __shared__ int cnt[256];
    __shared__ int cur[256];
    __shared__ int wsum[8];
    __shared__ int wsum2[4];
    __shared__ float Ws[H1 * H2];   // 2 KB
    __shared__ float hs[128][33];   // 16.9 KB
    __shared__ int s_wb, s_base, s_nh;
    const int b = blockIdx.x >> 1;
    const int h = blockIdx.x & 1;
    const int tid = threadIdx.x;
    const int lane = tid & 63;
    const int wid = tid >> 6;
    if (tid < 256) cnt[tid] = degc[(b << 8) + tid];   // degrees from k_mid
    for (int i = tid; i < H1 * H2; i += 512) Ws[i] = W2[i];
    // cross-bucket exclusive scan of final bucket counts -> wb
    const int own0 = (tid < NBUCK) ? bucket_cursor[tid] : 0;
    int incl0 = wave_scan_incl(own0, lane);
    if (lane == 63) wsum[wid] = incl0;
    __syncthreads();                                   // B1
    if (tid == 0) {
        int r = 0;
#pragma unroll
        for (int w = 0; w < 8; ++w) { const int t = wsum[w]; wsum[w] = r; r += t; }
    }
    __syncthreads();                                   // B2
    if (tid == b) s_wb = incl0 + wsum[wid] - own0;
    const int nb = bucket_cursor[b];
    const int rb = b * BCAP;
    int ownc = 0, inclc = 0;
    if (tid < 256) {
        ownc = cnt[tid];
        inclc = wave_scan_incl(ownc, lane);
        if (lane == 63) wsum2[wid] = inclc;
    }
    __syncthreads();                                   // B4
    if (tid == 0) {
        int r = 0;
#pragma unroll
        for (int w = 0; w < 4; ++w) { const int t = wsum2[w]; wsum2[w] = r; r += t; }
    }
    __syncthreads();                                   // B5
    const int wb = s_wb;
    if (tid < 256) {
        inclc += wsum2[wid];
        const int excl = inclc - ownc;
        cur[tid] = excl;
        const int v = (b << 8) + tid;
        if (v <= N_NODES) row_ptr[v] = wb + excl;      // covers row_ptr[N_NODES]
    }
    __syncthreads();                                   // B6
    if (tid == 0) {
        s_base = cur[h * 128];
        s_nh = (h ? nb : cur[128]) - cur[h * 128];
    }
    __syncthreads();                                   // B7
    const int base_h = s_base;
    const int nh = s_nh;
    for (int i = tid; i < nb; i += 512) {
        const int pk = ebuf[rb + i];
        const int dl = pk & 255;
        if ((dl >> 7) == h) {
            const int slot = atomicAdd(&cur[dl], 1);
            srt[slot - base_h] = pk >> 8;
        }
    }
    __syncthreads();                                   // B8
    for (int i = tid; i < nh; i += 512)
        col_idx[wb + base_h + i] = srt[i];
    const int nnl = tid >> 2;
    const int lq = tid & 3;
    const int nn = h * 128 + nnl;
    const int v = (b << 8) + nn;
    if (v < N_NODES) {
        const uint2* base = (const uint2*)u1q;
        const uint2 q = base[(size_t)v * 4 + lq];      // self-loop term
        float a0 = __builtin_amdgcn_cvt_f32_fp8(q.x, 0);
        float a1 = __builtin_amdgcn_cvt_f32_fp8(q.x, 1);
        float a2 = __builtin_amdgcn_cvt_f32_fp8(q.x, 2);
        float a3 = __builtin_amdgcn_cvt_f32_fp8(q.x, 3);
        float a4 = __builtin_amdgcn_cvt_f32_fp8(q.y, 0);
        float a5 = __builtin_amdgcn_cvt_f32_fp8(q.y, 1);
        float a6 = __builtin_amdgcn_cvt_f32_fp8(q.y, 2);
        float a7 = __builtin_amdgcn_cvt_f32_fp8(q.y, 3);
        const int cn = cnt[nn];
        const int e = cur[nn] - base_h;
        int j = e - cn;
        for (; j + 7 < e; j += 8) {
            const int s0 = srt[j + 0];
            const int s1 = srt[j + 1];
            const int s2 = srt[j + 2];
            const int s3 = srt[j + 3];
            const int s4 = srt[j + 4];
            const int s5 = srt[j + 5];
            const int s6 = srt[j + 6];
            const int s7 = srt[j + 7];
            const uint2 q0 = base[(size_t)s0 * 4 + lq];
            const uint2 q1 = base[(size_t)s1 * 4 + lq];
            const uint2 q2 = base[(size_t)s2 * 4 + lq];
            const uint2 q3 = base[(size_t)s3 * 4 + lq];
            const uint2 q4 = base[(size_t)s4 * 4 + lq];
            const uint2 q5 = base[(size_t)s5 * 4 + lq];
            const uint2 q6 = base[(size_t)s6 * 4 + lq];
            const uint2 q7 = base[(size_t)s7 * 4 + lq];
            ACC8(q0); ACC8(q1); ACC8(q2); ACC8(q3);
            ACC8(q4); ACC8(q5); ACC8(q6); ACC8(q7);
        }
        for (; j + 3 < e; j += 4) {
            const int s0 = srt[j + 0];
            const int s1 = srt[j + 1];
            const int s2 = srt[j + 2];
            const int s3 = srt[j + 3];
            const uint2 q0 = base[(size_t)s0 * 4 + lq];
            const uint2 q1 = base[(size_t)s1 * 4 + lq];
            const uint2 q2 = base[(size_t)s2 * 4 + lq];
            const uint2 q3 = base[(size_t)s3 * 4 + lq];
            ACC8(q0); ACC8(q1); ACC8(q2); ACC8(q3);
        }
        for (; j < e; ++j) {
            const uint2 qq = base[(size_t)srt[j] * 4 + lq];
            ACC8(qq);
        }
        const float dv = rsqrtf(1.0f + (float)cn);
        const float4 bb0 = ((const float4*)b1)[lq * 2];
        const float4 bb1 = ((const float4*)b1)[lq * 2 + 1];
        float* hp = &hs[nnl][lq * 8];
        hp[0] = fmaxf(fmaf(a0, dv, bb0.x), 0.0f);
        hp[1] = fmaxf(fmaf(a1, dv, bb0.y), 0.0f);
        hp[2] = fmaxf(fmaf(a2, dv, bb0.z), 0.0f);
        hp[3] = fmaxf(fmaf(a3, dv, bb0.w), 0.0f);
        hp[4] = fmaxf(fmaf(a4, dv, bb1.x), 0.0f);
        hp[5] = fmaxf(fmaf(a5, dv, bb1.y), 0.0f);
        hp[6] = fmaxf(fmaf(a6, dv, bb1.z), 0.0f);
        hp[7] = fmaxf(fmaf(a7, dv, bb1.w), 0.0f);
        if (lq == 0) hs[nnl][32] = dv;
    }
    __syncthreads();                                   // B9
    {
        const int nn2 = tid >> 2;
        const int jq = tid & 3;
        const int v2 = (b << 8) + h * 128 + nn2;
        if (v2 < N_NODES) {
            const int j0 = jq * 4;
            const float dv = hs[nn2][32];
            float s0 = 0.f, s1 = 0.f, s2 = 0.f, s3 = 0.f;
#pragma unroll
            for (int k = 0; k < H1; ++k) {
                const float hk = hs[nn2][k];
                s0 = fmaf(hk, Ws[k * H2 + j0 + 0], s0);
                s1 = fmaf(hk, Ws[k * H2 + j0 + 1], s1);
                s2 = fmaf(hk, Ws[k * H2 + j0 + 2], s2);
                s3 = fmaf(hk, Ws[k * H2 + j0 + 3], s3);
            }
            uint2 o;
            o.x = (unsigned int)f2bf(s0 * dv) | ((unsigned int)f2bf(s1 * dv) << 16);
            o.y = (unsigned int)f2bf(s2 * dv) | ((unsigned int)f2bf(s3 * dv) << 16);
            ((uint2*)u2b)[(size_t)v2 * 4 + jq] = o;
        }
    }
}

// ---------------- fused pull2 + classifier (unchanged) -----------------------

#define ACC4(Q) do { \
    a0 += bf2f((unsigned short)(Q).x); \
    a1 += bf2f((unsigned short)((Q).x >> 16)); \
    a2 += bf2f((unsigned short)(Q).y); \
    a3 += bf2f((unsigned short)((Q).y >> 16)); \
} while (0)

__global__ __launch_bounds__(256) void k_pull2f(const int* __restrict__ row_ptr,
                                                const int* __restrict__ col_idx,
                                                const float* __restrict__ dinv,
                                                const unsigned int* __restrict__ u2b,
                                                const float* __restrict__ b2,
                                                const float* __restrict__ Wc,
                                                const float* __restrict__ bc,
                                                float* __restrict__ out) {
    __shared__ float hs[P_NODES][17];
    __shared__ float Wcs[H2 * NC];  // 128
    __shared__ float bcs[NC];
    __shared__ int lidx[P_CAP];     // 12 KB
    const int tid = threadIdx.x;
    if (tid < H2 * NC) Wcs[tid] = Wc[tid];
    if (tid < NC) bcs[tid] = bc[tid];
    const int v0 = blockIdx.x * P_NODES;
    const int base_off = row_ptr[v0];
    const int range = row_ptr[v0 + P_NODES] - base_off;
    const bool ovf = (range > P_CAP);
    const int stg = ovf ? 0 : range;
    for (int j = tid; j < stg; j += 256) lidx[j] = col_idx[base_off + j];
    __syncthreads();
    const int n = tid >> 3;
    const int half = (tid >> 2) & 1;
    const int lq = tid & 3;
    const int v = v0 + n;
    const uint2* base = (const uint2*)u2b;
    float a0 = 0.f, a1 = 0.f, a2 = 0.f, a3 = 0.f;
    if (half == 0) {
        const uint2 q = base[(size_t)v * 4 + lq];
        a0 = bf2f((unsigned short)q.x); a1 = bf2f((unsigned short)(q.x >> 16));
        a2 = bf2f((unsigned short)q.y); a3 = bf2f((unsigned short)(q.y >> 16));
    }
    const int beg = row_ptr[v] - base_off;
    const int end = row_ptr[v + 1] - base_off;
    int i = beg + half;
    if (!ovf) {
        for (; i + 14 < end; i += 16) {
            const int s0 = lidx[i];
            const int s1 = lidx[i + 2];
            const int s2 = lidx[i + 4];
            const int s3 = lidx[i + 6];
            const int s4 = lidx[i + 8];
            const int s5 = lidx[i + 10];
            const int s6 = lidx[i + 12];
            const int s7 = lidx[i + 14];
            const uint2 q0 = base[(size_t)s0 * 4 + lq];
            const uint2 q1 = base[(size_t)s1 * 4 + lq];
            const uint2 q2 = base[(size_t)s2 * 4 + lq];
            const uint2 q3 = base[(size_t)s3 * 4 + lq];
            const uint2 q4 = base[(size_t)s4 * 4 + lq];
            const uint2 q5 = base[(size_t)s5 * 4 + lq];
            const uint2 q6 = base[(size_t)s6 * 4 + lq];
            const uint2 q7 = base[(size_t)s7 * 4 + lq];
            ACC4(q0); ACC4(q1); ACC4(q2); ACC4(q3);
            ACC4(q4); ACC4(q5); ACC4(q6); ACC4(q7);
        }
        for (; i + 6 < end; i += 8) {
            const int s0 = lidx[i];
            const int s1 = lidx[i + 2];
            const int s2 = lidx[i + 4];
            const int s3 = lidx[i + 6];
            const uint2 q0 = base[(size_t)s0 * 4 + lq];
            const uint2 q1 = base[(size_t)s1 * 4 + lq];
            const uint2 q2 = base[(size_t)s2 * 4 + lq];
            const uint2 q3 = base[(size_t)s3 * 4 + lq];
            ACC4(q0); ACC4(q1); ACC4(q2); ACC4(q3);
        }
        for (; i < end; i += 2) {
            const uint2 qq = base[(size_t)lidx[i] * 4 + lq];
            ACC4(qq);
        }
    } else {
        const int* gp = col_idx + base_off;
        for (; i + 14 < end; i += 16) {
            const int s0 = gp[i];
            const int s1 = gp[i + 2];
            const int s2 = gp[i + 4];
            const int s3 = gp[i + 6];
            const int s4 = gp[i + 8];
            const int s5 = gp[i + 10];
            const int s6 = gp[i + 12];
            const int s7 = gp[i + 14];
            const uint2 q0 = base[(size_t)s0 * 4 + lq];
            const uint2 q1 = base[(size_t)s1 * 4 + lq];
            const uint2 q2 = base[(size_t)s2 * 4 + lq];
            const uint2 q3 = base[(size_t)s3 * 4 + lq];
            const uint2 q4 = base[(size_t)s4 * 4 + lq];
            const uint2 q5 = base[(size_t)s5 * 4 + lq];
            const uint2 q6 = base[(size_t)s6 * 4 + lq];
            const uint2 q7 = base[(size_t)s7 * 4 + lq];
            ACC4(q0); ACC4(q1); ACC4(q2); ACC4(q3);
            ACC4(q4); ACC4(q5); ACC4(q6); ACC4(q7);
        }
        for (; i < end; i += 2) {
            const uint2 qq = base[(size_t)gp[i] * 4 + lq];
            ACC4(qq);
        }
    }
    a0 += __shfl_xor(a0, 4, 64); a1 += __shfl_xor(a1, 4, 64);
    a2 += __shfl_xor(a2, 4, 64); a3 += __shfl_xor(a3, 4, 64);
    if (half == 0) {
        const float dv = dinv[v];
        const float4 bb = ((const float4*)b2)[lq];
        float* hp = &hs[n][lq * 4];
        hp[0] = fmaxf(fmaf(a0, dv, bb.x), 0.0f);
        hp[1] = fmaxf(fmaf(a1, dv, bb.y), 0.0f);
        hp[2] = fmaxf(fmaf(a2, dv, bb.z), 0.0f);
        hp[3] = fmaxf(fmaf(a3, dv, bb.w), 0.0f);
    }
    __syncthreads();
    if (tid < P_NODES) {
        const int vv = v0 + tid;
        float lg[NC];
#pragma unroll
        for (int j = 0; j < NC; ++j) lg[j] = bcs[j];
#pragma unroll
        for (int k = 0; k < H2; ++k) {
            const float hk = hs[tid][k];
#pragma unroll
            for (int j = 0; j < NC; ++j)
                lg[j] = fmaf(hk, Wcs[k * NC + j], lg[j]);
        }
        float m = lg[0];
#pragma unroll
        for (int j = 1; j < NC; ++j) m = fmaxf(m, lg[j]);
        float s = 0.0f;
#pragma unroll
        for (int j = 0; j < NC; ++j) s += expf(lg[j] - m);
        const float lse = logf(s) + m;
        float4 o0, o1;
        o0.x = lg[0] - lse; o0.y = lg[1] - lse;
        o0.z = lg[2] - lse; o0.w = lg[3] - lse;
        o1.x = lg[4] - lse; o1.y = lg[5] - lse;
        o1.z = lg[6] - lse; o1.w = lg[7] - lse;
        float4* op = (float4*)(out + (size_t)vv * NC);
        op[0] = o0; op[1] = o1;
    }
}

// ---------------- host launch ----------------

extern "C" void kernel_launch(void* const* d_in, const int* in_sizes, int n_in,
                              void* d_out, int out_size, void* d_ws, size_t ws_size,
                              hipStream_t stream) {
    const float* x   = (const float*)d_in[0];
    const int*   ei  = (const int*)d_in[1];
    const float* W1  = (const float*)d_in[2];
    const float* b1  = (const float*)d_in[3];
    const float* W2  = (const float*)d_in[4];
    const float* b2  = (const float*)d_in[5];
    const float* Wc  = (const float*)d_in[6];
    const float* bc  = (const float*)d_in[7];
    float* out = (float*)d_out;

    // workspace layout (int units). ~41.2 MB total.
    int*   bucket_cursor = (int*)d_ws;                       // 512
    float* dinv          = (float*)(bucket_cursor + 512);    // 100000
    int*   degc          = (int*)dinv + 100000;              // 100096
    int*   row_ptr       = degc + 100096;                    // 100016 (100001 used)
    int*   col_idx       = row_ptr + 100016;                 // 3200000
    unsigned int* u1q    = (unsigned int*)(col_idx + 3200000); // 800000 dwords
    unsigned int* u2b    = u1q + 800000;                     // 800000 dwords
    int*   ebuf          = (int*)(u2b + 800000);             // NBUCK*BCAP = 4804608
    // y16 (bf16 x@W1, 6.4 MB) aliases col_idx's space: y16 dead before fuse1
    // writes col_idx; lifetimes disjoint across kernel boundaries.
    unsigned short* y16  = (unsigned short*)col_idx;         // 100096*32 shorts

    hipMemsetAsync(bucket_cursor, 0, 512 * sizeof(int), stream);
    k_pre <<<NSB + NBUCK, 512, 0, stream>>>(ei, x, W1, bucket_cursor, ebuf, y16);
    k_mid <<<NBUCK, 512, 0, stream>>>(ebuf, bucket_cursor, y16, degc, dinv, u1q);
    k_fuse1<<<NBUCK * 2, 512, 0, stream>>>(ebuf, bucket_cursor, degc, u1q, b1, W2, row_ptr, col_idx, u2b);
    k_pull2f<<<N_NODES / P_NODES, 256, 0, stream>>>(row_ptr, col_idx, dinv, u2b, b2, Wc, bc, out);
}

// Round 10
// 200.726 us; speedup vs baseline: 6.3659x; 1.0060x over previous
//
#include <hip/hip_runtime.h>
#include <math.h>

#define N_NODES 100000
#define N_EDGES 3200000
#define D_FEAT 128
#define H1 32
#define H2 16
#define NC 8

#define NB2 782            // buckets of 128 dst nodes: ceil(100000/128)
#define BCAP2 6144         // ebuf slots per 128-bucket (mean 4093, +32 sigma)
#define HCAP 6144          // srt slots per fuse1 block (one 128-bucket)
#define EPB 4096           // edges per scatter block
#define EPT 8              // edges per thread (EPB / 512)
#define NSB ((N_EDGES + EPB - 1) / EPB)   // 782 scatter blocks

#define P_NODES 32         // nodes per pull2 block
#define P_CAP 3072         // staged col_idx slots in pull2

typedef short s16x8 __attribute__((ext_vector_type(8)));
typedef float f32x4 __attribute__((ext_vector_type(4)));

__device__ inline unsigned short f2bf(float f) {
    unsigned int u = __float_as_uint(f);
    u += 0x7FFF + ((u >> 16) & 1);
    return (unsigned short)(u >> 16);
}
__device__ inline float bf2f(unsigned short h) {
    return __uint_as_float((unsigned int)h << 16);
}

// 64-lane inclusive scan, no barriers
__device__ inline int wave_scan_incl(int v, int lane) {
#pragma unroll
    for (int off = 1; off < 64; off <<= 1) {
        const int t = __shfl_up(v, off, 64);
        if (lane >= off) v += t;
    }
    return v;
}

// ---------------- k_pre: scatter blocks [0,NSB) + gemm blocks [NSB,NSB+391) --
// Scatter: counting sort into 128-dst buckets (782-wide two-chunk scans).
// Gemm: y16 = bf16(x@W1) unscaled. Complementary pipes co-resident (m114).

__global__ __launch_bounds__(512) void k_pre(const int* __restrict__ ei,
                                             const float* __restrict__ x,
                                             const float* __restrict__ W1,
                                             int* __restrict__ bucket_cursor,
                                             int* __restrict__ ebuf,
                                             unsigned short* __restrict__ y16) {
    __shared__ union {
        struct {
            int hist[NB2], lofs[NB2], rank[NB2], gb[NB2];   // 12.5 KB
            int wsumA[8], wsumB[8], tot, is64;
            int pay[EPB];                // 16 KB
            unsigned short pbk[EPB];     // 8 KB
        } sc;                            // ~37 KB
        struct {
            unsigned short wf[2 * 4 * 64 * 8];  // 8 KB W1 fragments
            float os[8][16][33];                // 16.9 KB
        } gm;                            // ~25 KB
    } u;
    const int tid = threadIdx.x;
    const int lane = tid & 63;
    const int wid = tid >> 6;

    if (blockIdx.x >= NSB) {
        // ---------------- gemm path (unchanged from R9) ----------------
        const int gb_ = blockIdx.x - NSB;
        for (int idx = tid; idx < 2 * 4 * 64 * 8; idx += 512) {
            const int j  = idx & 7;
            const int ln = (idx >> 3) & 63;
            const int kk = (idx >> 9) & 3;
            const int nt = idx >> 11;
            const int k = kk * 32 + ((ln >> 4) << 3) + j;
            const int n = nt * 16 + (ln & 15);
            u.gm.wf[idx] = f2bf(W1[k * H1 + n]);
        }
        __syncthreads();
        const int w = tid >> 6;
        const int m = lane & 15;
        const int quad = lane >> 4;
        const int rl = lane >> 2;
        const int seg = lane & 3;
        const s16x8* bf = (const s16x8*)u.gm.wf;
#pragma unroll
        for (int t = 0; t < 2; ++t) {
            const int row0 = (gb_ << 8) + (w * 2 + t) * 16;
            const bool act = (row0 < N_NODES);   // 160 % 16 == 0: full tiles
            if (act) {
                f32x4 acc0 = {0.f, 0.f, 0.f, 0.f};
                f32x4 acc1 = {0.f, 0.f, 0.f, 0.f};
#pragma unroll
                for (int kk = 0; kk < 4; ++kk) {
                    const float* xp = x + (size_t)(row0 + m) * D_FEAT + kk * 32 + quad * 8;
                    const float4 p0 = ((const float4*)xp)[0];
                    const float4 p1 = ((const float4*)xp)[1];
                    s16x8 a;
                    a[0] = (short)f2bf(p0.x); a[1] = (short)f2bf(p0.y);
                    a[2] = (short)f2bf(p0.z); a[3] = (short)f2bf(p0.w);
                    a[4] = (short)f2bf(p1.x); a[5] = (short)f2bf(p1.y);
                    a[6] = (short)f2bf(p1.z); a[7] = (short)f2bf(p1.w);
                    acc0 = __builtin_amdgcn_mfma_f32_16x16x32_bf16(a, bf[kk * 64 + lane], acc0, 0, 0, 0);
                    acc1 = __builtin_amdgcn_mfma_f32_16x16x32_bf16(a, bf[(4 + kk) * 64 + lane], acc1, 0, 0, 0);
                }
#pragma unroll
                for (int r = 0; r < 4; ++r) {
                    u.gm.os[w][quad * 4 + r][m]      = acc0[r];
                    u.gm.os[w][quad * 4 + r][16 + m] = acc1[r];
                }
            }
            __syncthreads();
            if (act) {
                const int row = row0 + rl;
                const float* p = &u.gm.os[w][rl][seg * 8];
                uint4 o;
                o.x = (unsigned int)f2bf(p[0]) | ((unsigned int)f2bf(p[1]) << 16);
                o.y = (unsigned int)f2bf(p[2]) | ((unsigned int)f2bf(p[3]) << 16);
                o.z = (unsigned int)f2bf(p[4]) | ((unsigned int)f2bf(p[5]) << 16);
                o.w = (unsigned int)f2bf(p[6]) | ((unsigned int)f2bf(p[7]) << 16);
                *(uint4*)(y16 + (size_t)row * 32 + seg * 8) = o;
            }
            __syncthreads();
        }
        return;
    }

    // ---------------- scatter path (128-dst buckets) ----------------
    for (int i = tid; i < NB2; i += 512) { u.sc.hist[i] = 0; u.sc.rank[i] = 0; }
    if (tid < 64) {                          // wave-local is64 detect
        int v = ei[2 * tid + 1];
#pragma unroll
        for (int off = 1; off < 64; off <<= 1) v |= __shfl_xor(v, off, 64);
        if (tid == 0) u.sc.is64 = (v == 0) ? 1 : 0;
    }
    __syncthreads();
    const int e0 = blockIdx.x * EPB;
    const int n = min(EPB, N_EDGES - e0);    // always even
    const bool is64 = (u.sc.is64 != 0);
    int rs[EPT], rd[EPT];
    if (is64) {
#pragma unroll
        for (int k = 0; k < EPT / 2; ++k) {
            const int i = 2 * (tid + k * 512);
            if (i < n) {
                const int e = e0 + i;
                const int4 s = *(const int4*)&ei[2 * e];
                const int4 d = *(const int4*)&ei[2 * N_EDGES + 2 * e];
                rs[2 * k] = s.x; rs[2 * k + 1] = s.z;
                rd[2 * k] = d.x; rd[2 * k + 1] = d.z;
                atomicAdd(&u.sc.hist[d.x >> 7], 1);
                atomicAdd(&u.sc.hist[d.z >> 7], 1);
            }
        }
    } else {
#pragma unroll
        for (int k = 0; k < EPT / 2; ++k) {
            const int i = 2 * (tid + k * 512);
            if (i < n) {
                const int e = e0 + i;
                const int2 s = *(const int2*)&ei[e];
                const int2 d = *(const int2*)&ei[N_EDGES + e];
                rs[2 * k] = s.x; rs[2 * k + 1] = s.y;
                rd[2 * k] = d.x; rd[2 * k + 1] = d.y;
                atomicAdd(&u.sc.hist[d.x >> 7], 1);
                atomicAdd(&u.sc.hist[d.y >> 7], 1);
            }
        }
    }
    __syncthreads();
    // two-chunk 782-wide scan: chunk 1 [0,512)
    const int own0 = u.sc.hist[tid];
    int incl0 = wave_scan_incl(own0, lane);
    if (lane == 63) u.sc.wsumA[wid] = incl0;
    __syncthreads();
    if (tid == 0) {
        int r = 0;
#pragma unroll
        for (int w = 0; w < 8; ++w) { const int t = u.sc.wsumA[w]; u.sc.wsumA[w] = r; r += t; }
        u.sc.tot = r;
    }
    __syncthreads();
    incl0 += u.sc.wsumA[wid];
    u.sc.lofs[tid] = incl0 - own0;
    // chunk 2 [512, 782)
    const int own1 = (tid < NB2 - 512) ? u.sc.hist[512 + tid] : 0;
    int incl1 = wave_scan_incl(own1, lane);
    if (lane == 63) u.sc.wsumB[wid] = incl1;
    __syncthreads();
    if (tid == 0) {
        int r = 0;
#pragma unroll
        for (int w = 0; w < 8; ++w) { const int t = u.sc.wsumB[w]; u.sc.wsumB[w] = r; r += t; }
    }
    __syncthreads();
    incl1 += u.sc.wsumB[wid] + u.sc.tot;
    if (tid < NB2 - 512) u.sc.lofs[512 + tid] = incl1 - own1;
    // global cursor reservation per bucket
    for (int i = tid; i < NB2; i += 512) {
        const int ownI = u.sc.hist[i];
        if (ownI > 0) u.sc.gb[i] = i * BCAP2 + atomicAdd(&bucket_cursor[i], ownI);
    }
    __syncthreads();
#pragma unroll
    for (int k = 0; k < EPT / 2; ++k) {
        const int i = 2 * (tid + k * 512);
        if (i < n) {
#pragma unroll
            for (int j = 0; j < 2; ++j) {
                const int b = rd[2 * k + j] >> 7;
                const int p = u.sc.lofs[b] + atomicAdd(&u.sc.rank[b], 1);
                u.sc.pay[p] = (rs[2 * k + j] << 8) | (rd[2 * k + j] & 255);
                u.sc.pbk[p] = (unsigned short)b;
            }
        }
    }
    __syncthreads();
    for (int p = tid; p < n; p += 512) {
        const int b = u.sc.pbk[p];
        ebuf[u.sc.gb[b] + (p - u.sc.lofs[b])] = u.sc.pay[p];
    }
}

// ---------------- k_mid: degree + dinv-scale + fp8 pack + bbase scan ---------
// 391 blocks x 512; block b handles 128-buckets 2b,2b+1 (nodes [b*256,+256)).
// Block 0 additionally computes bbase[0..NB2) = exclusive bucket prefix.

__global__ __launch_bounds__(512) void k_mid(const int* __restrict__ ebuf,
                                             const int* __restrict__ bucket_cursor,
                                             const unsigned short* __restrict__ y16,
                                             int* __restrict__ degc,
                                             float* __restrict__ dinv,
                                             int* __restrict__ bbase,
                                             unsigned int* __restrict__ u1q) {
    __shared__ int cnt[256];
    __shared__ int wsA[8], wsB[8];
    __shared__ int tt;
    const int b = blockIdx.x;
    const int tid = threadIdx.x;
    if (tid < 256) cnt[tid] = 0;
    __syncthreads();
#pragma unroll
    for (int j = 0; j < 2; ++j) {
        const int b2 = 2 * b + j;
        const int nbj = bucket_cursor[b2];
        const int rbj = b2 * BCAP2;
        for (int i = tid; i < nbj; i += 512)
            atomicAdd(&cnt[ebuf[rbj + i] & 255], 1);   // bit7 = bucket parity
    }
    __syncthreads();
    if (tid < 256) {
        const int v = (b << 8) + tid;
        const int cn = cnt[tid];
        degc[v] = cn;
        if (v < N_NODES) {
            const float dv = rsqrtf(1.0f + (float)cn);
            dinv[v] = dv;
            unsigned int r[16];
            const uint4* yp = (const uint4*)(y16 + (size_t)v * 32);
            *(uint4*)&r[0]  = yp[0];
            *(uint4*)&r[4]  = yp[1];
            *(uint4*)&r[8]  = yp[2];
            *(uint4*)&r[12] = yp[3];
            unsigned int wq[8];
#pragma unroll
            for (int j = 0; j < 8; ++j) {
                const float c0 = bf2f((unsigned short)r[2 * j]) * dv;
                const float c1 = bf2f((unsigned short)(r[2 * j] >> 16)) * dv;
                const float c2 = bf2f((unsigned short)r[2 * j + 1]) * dv;
                const float c3 = bf2f((unsigned short)(r[2 * j + 1] >> 16)) * dv;
                unsigned int pk = __builtin_amdgcn_cvt_pk_fp8_f32(c0, c1, 0u, false);
                wq[j] = __builtin_amdgcn_cvt_pk_fp8_f32(c2, c3, pk, true);
            }
            uint4 oa; oa.x = wq[0]; oa.y = wq[1]; oa.z = wq[2]; oa.w = wq[3];
            uint4 ob; ob.x = wq[4]; ob.y = wq[5]; ob.z = wq[6]; ob.w = wq[7];
            ((uint4*)u1q)[(size_t)v * 2]     = oa;
            ((uint4*)u1q)[(size_t)v * 2 + 1] = ob;
        }
    }
    if (b == 0) {                        // bbase: exclusive scan of 782 counts
        const int lane = tid & 63, wid = tid >> 6;
        const int o0 = bucket_cursor[tid];
        int i0 = wave_scan_incl(o0, lane);
        if (lane == 63) wsA[wid] = i0;
        __syncthreads();
        if (tid == 0) {
            int r = 0;
#pragma unroll
            for (int w = 0; w < 8; ++w) { const int t = wsA[w]; wsA[w] = r; r += t; }
            tt = r;
        }
        __syncthreads();
        i0 += wsA[wid];
        bbase[tid] = i0 - o0;
        const int o1 = (tid < NB2 - 512) ? bucket_cursor[512 + tid] : 0;
        int i1 = wave_scan_incl(o1, lane);
        if (lane == 63) wsB[wid] = i1;
        __syncthreads();
        if (tid == 0) {
            int r = 0;
#pragma unroll
            for (int w = 0; w < 8; ++w) { const int t = wsB[w]; wsB[w] = r; r += t; }
        }
        __syncthreads();
        i1 += wsB[wid] + tt;
        if (tid < NB2 - 512) bbase[512 + tid] = i1 - o1;
    }
}

// ---------------- fused sort + pull1 + GEMM2 (one 128-bucket per block) ------
// ebuf read ONCE per block (own region only); scans 128-wide; wb from bbase.

#define ACC8(Q) do { \
    a0 += __builtin_amdgcn_cvt_f32_fp8((Q).x, 0); \
    a1 += __builtin_amdgcn_cvt_f32_fp8((Q).x, 1); \
    a2 += __builtin_amdgcn_cvt_f32_fp8((Q).x, 2); \
    a3 += __builtin_amdgcn_cvt_f32_fp8((Q).x, 3); \
    a4 += __builtin_amdgcn_cvt_f32_fp8((Q).y, 0); \
    a5 += __builtin_amdgcn_cvt_f32_fp8((Q).y, 1); \
    a6 += __builtin_amdgcn_cvt_f32_fp8((Q).y, 2); \
    a7 += __builtin_amdgcn_cvt_f32_fp8((Q).y, 3); \
} while (0)

__global__ __launch_bounds__(512) void k_fuse1(const int* __restrict__ ebuf,
                                               const int* __restrict__ bucket_cursor,
                                               const int* __restrict__ degc,
                                               const int* __restrict__ bbase,
                                               const unsigned int* __restrict__ u1q,
                                               const float* __restrict__ b1,
                                               const float* __restrict__ W2,
                                               int* __restrict__ row_ptr,
                                               int* __restrict__ col_idx,
                                               unsigned int* __restrict__ u2b) {
    __shared__ int srt[HCAP];       // 24 KB sorted src of own bucket
    __shared__ int cnt[128];
    __shared__ int cur[128];
    __shared__ int wsum2[2];
    __shared__ float Ws[H1 * H2];   // 2 KB
    __shared__ float hs[128][33];   // 16.9 KB
    const int b2 = blockIdx.x;
    const int tid = threadIdx.x;
    const int lane = tid & 63;
    const int wid = tid >> 6;
    if (tid < 128) cnt[tid] = degc[(b2 << 7) + tid];
    for (int i = tid; i < H1 * H2; i += 512) Ws[i] = W2[i];
    const int wb = bbase[b2];
    const int nb = bucket_cursor[b2];
    const int rb = b2 * BCAP2;
    __syncthreads();
    // 128-wide scan of cnt (waves 0,1)
    int ownc = 0, inclc = 0;
    if (tid < 128) {
        ownc = cnt[tid];
        inclc = wave_scan_incl(ownc, lane);
        if (lane == 63) wsum2[wid] = inclc;
    }
    __syncthreads();
    if (tid < 128) {
        if (wid == 1) inclc += wsum2[0];
        const int excl = inclc - ownc;
        cur[tid] = excl;
        const int v = (b2 << 7) + tid;
        if (v <= N_NODES) row_ptr[v] = wb + excl;   // covers row_ptr[N_NODES]
    }
    __syncthreads();
    // scatter own bucket's edges into srt (local slots), sorted by dst
    for (int i = tid; i < nb; i += 512) {
        const int pk = ebuf[rb + i];
        const int slot = atomicAdd(&cur[pk & 127], 1);
        srt[slot] = pk >> 8;
    }
    __syncthreads();
    // coalesced col_idx write for pull2
    for (int i = tid; i < nb; i += 512)
        col_idx[wb + i] = srt[i];
    // per-node register gather (4 lanes/node, 8-deep pipeline)
    const int nn = tid >> 2;        // node-in-bucket 0..127
    const int lq = tid & 3;         // feature lane (8 fp8 = 8B each)
    const int v = (b2 << 7) + nn;
    if (v < N_NODES) {
        const uint2* base = (const uint2*)u1q;
        const uint2 q = base[(size_t)v * 4 + lq];      // self-loop term
        float a0 = __builtin_amdgcn_cvt_f32_fp8(q.x, 0);
        float a1 = __builtin_amdgcn_cvt_f32_fp8(q.x, 1);
        float a2 = __builtin_amdgcn_cvt_f32_fp8(q.x, 2);
        float a3 = __builtin_amdgcn_cvt_f32_fp8(q.x, 3);
        float a4 = __builtin_amdgcn_cvt_f32_fp8(q.y, 0);
        float a5 = __builtin_amdgcn_cvt_f32_fp8(q.y, 1);
        float a6 = __builtin_amdgcn_cvt_f32_fp8(q.y, 2);
        float a7 = __builtin_amdgcn_cvt_f32_fp8(q.y, 3);
        const int cn = cnt[nn];
        const int e = cur[nn];                         // local inclusive end
        int j = e - cn;                                // local start
        for (; j + 7 < e; j += 8) {                    // 8 gathers in flight
            const int s0 = srt[j + 0];
            const int s1 = srt[j + 1];
            const int s2 = srt[j + 2];
            const int s3 = srt[j + 3];
            const int s4 = srt[j + 4];
            const int s5 = srt[j + 5];
            const int s6 = srt[j + 6];
            const int s7 = srt[j + 7];
            const uint2 q0 = base[(size_t)s0 * 4 + lq];
            const uint2 q1 = base[(size_t)s1 * 4 + lq];
            const uint2 q2 = base[(size_t)s2 * 4 + lq];
            const uint2 q3 = base[(size_t)s3 * 4 + lq];
            const uint2 q4 = base[(size_t)s4 * 4 + lq];
            const uint2 q5 = base[(size_t)s5 * 4 + lq];
            const uint2 q6 = base[(size_t)s6 * 4 + lq];
            const uint2 q7 = base[(size_t)s7 * 4 + lq];
            ACC8(q0); ACC8(q1); ACC8(q2); ACC8(q3);
            ACC8(q4); ACC8(q5); ACC8(q6); ACC8(q7);
        }
        for (; j + 3 < e; j += 4) {
            const int s0 = srt[j + 0];
            const int s1 = srt[j + 1];
            const int s2 = srt[j + 2];
            const int s3 = srt[j + 3];
            const uint2 q0 = base[(size_t)s0 * 4 + lq];
            const uint2 q1 = base[(size_t)s1 * 4 + lq];
            const uint2 q2 = base[(size_t)s2 * 4 + lq];
            const uint2 q3 = base[(size_t)s3 * 4 + lq];
            ACC8(q0); ACC8(q1); ACC8(q2); ACC8(q3);
        }
        for (; j < e; ++j) {
            const uint2 qq = base[(size_t)srt[j] * 4 + lq];
            ACC8(qq);
        }
        const float dv = rsqrtf(1.0f + (float)cn);
        const float4 bb0 = ((const float4*)b1)[lq * 2];
        const float4 bb1 = ((const float4*)b1)[lq * 2 + 1];
        float* hp = &hs[nn][lq * 8];
        hp[0] = fmaxf(fmaf(a0, dv, bb0.x), 0.0f);
        hp[1] = fmaxf(fmaf(a1, dv, bb0.y), 0.0f);
        hp[2] = fmaxf(fmaf(a2, dv, bb0.z), 0.0f);
        hp[3] = fmaxf(fmaf(a3, dv, bb0.w), 0.0f);
        hp[4] = fmaxf(fmaf(a4, dv, bb1.x), 0.0f);
        hp[5] = fmaxf(fmaf(a5, dv, bb1.y), 0.0f);
        hp[6] = fmaxf(fmaf(a6, dv, bb1.z), 0.0f);
        hp[7] = fmaxf(fmaf(a7, dv, bb1.w), 0.0f);
        if (lq == 0) hs[nn][32] = dv;
    }
    __syncthreads();
    {
        const int nn2 = tid >> 2;
        const int jq = tid & 3;
        const int v2 = (b2 << 7) + nn2;
        if (v2 < N_NODES) {
            const int j0 = jq * 4;
            const float dv = hs[nn2][32];
            float s0 = 0.f, s1 = 0.f, s2 = 0.f, s3 = 0.f;
#pragma unroll
            for (int k = 0; k < H1; ++k) {
                const float hk = hs[nn2][k];
                s0 = fmaf(hk, Ws[k * H2 + j0 + 0], s0);
                s1 = fmaf(hk, Ws[k * H2 + j0 + 1], s1);
                s2 = fmaf(hk, Ws[k * H2 + j0 + 2], s2);
                s3 = fmaf(hk, Ws[k * H2 + j0 + 3], s3);
            }
            uint2 o;
            o.x = (unsigned int)f2bf(s0 * dv) | ((unsigned int)f2bf(s1 * dv) << 16);
            o.y = (unsigned int)f2bf(s2 * dv) | ((unsigned int)f2bf(s3 * dv) << 16);
            ((uint2*)u2b)[(size_t)v2 * 4 + jq] = o;
        }
    }
}

// ---------------- fused pull2 + classifier (unchanged) -----------------------

#define ACC4(Q) do { \
    a0 += bf2f((unsigned short)(Q).x); \
    a1 += bf2f((unsigned short)((Q).x >> 16)); \
    a2 += bf2f((unsigned short)(Q).y); \
    a3 += bf2f((unsigned short)((Q).y >> 16)); \
} while (0)

__global__ __launch_bounds__(256) void k_pull2f(const int* __restrict__ row_ptr,
                                                const int* __restrict__ col_idx,
                                                const float* __restrict__ dinv,
                                                const unsigned int* __restrict__ u2b,
                                                const float* __restrict__ b2,
                                                const float* __restrict__ Wc,
                                                const float* __restrict__ bc,
                                                float* __restrict__ out) {
    __shared__ float hs[P_NODES][17];
    __shared__ float Wcs[H2 * NC];  // 128
    __shared__ float bcs[NC];
    __shared__ int lidx[P_CAP];     // 12 KB
    const int tid = threadIdx.x;
    if (tid < H2 * NC) Wcs[tid] = Wc[tid];
    if (tid < NC) bcs[tid] = bc[tid];
    const int v0 = blockIdx.x * P_NODES;
    const int base_off = row_ptr[v0];
    const int range = row_ptr[v0 + P_NODES] - base_off;
    const bool ovf = (range > P_CAP);
    const int stg = ovf ? 0 : range;
    for (int j = tid; j < stg; j += 256) lidx[j] = col_idx[base_off + j];
    __syncthreads();
    const int n = tid >> 3;
    const int half = (tid >> 2) & 1;
    const int lq = tid & 3;
    const int v = v0 + n;
    const uint2* base = (const uint2*)u2b;
    float a0 = 0.f, a1 = 0.f, a2 = 0.f, a3 = 0.f;
    if (half == 0) {
        const uint2 q = base[(size_t)v * 4 + lq];
        a0 = bf2f((unsigned short)q.x); a1 = bf2f((unsigned short)(q.x >> 16));
        a2 = bf2f((unsigned short)q.y); a3 = bf2f((unsigned short)(q.y >> 16));
    }
    const int beg = row_ptr[v] - base_off;
    const int end = row_ptr[v + 1] - base_off;
    int i = beg + half;
    if (!ovf) {
        for (; i + 14 < end; i += 16) {
            const int s0 = lidx[i];
            const int s1 = lidx[i + 2];
            const int s2 = lidx[i + 4];
            const int s3 = lidx[i + 6];
            const int s4 = lidx[i + 8];
            const int s5 = lidx[i + 10];
            const int s6 = lidx[i + 12];
            const int s7 = lidx[i + 14];
            const uint2 q0 = base[(size_t)s0 * 4 + lq];
            const uint2 q1 = base[(size_t)s1 * 4 + lq];
            const uint2 q2 = base[(size_t)s2 * 4 + lq];
            const uint2 q3 = base[(size_t)s3 * 4 + lq];
            const uint2 q4 = base[(size_t)s4 * 4 + lq];
            const uint2 q5 = base[(size_t)s5 * 4 + lq];
            const uint2 q6 = base[(size_t)s6 * 4 + lq];
            const uint2 q7 = base[(size_t)s7 * 4 + lq];
            ACC4(q0); ACC4(q1); ACC4(q2); ACC4(q3);
            ACC4(q4); ACC4(q5); ACC4(q6); ACC4(q7);
        }
        for (; i + 6 < end; i += 8) {
            const int s0 = lidx[i];
            const int s1 = lidx[i + 2];
            const int s2 = lidx[i + 4];
            const int s3 = lidx[i + 6];
            const uint2 q0 = base[(size_t)s0 * 4 + lq];
            const uint2 q1 = base[(size_t)s1 * 4 + lq];
            const uint2 q2 = base[(size_t)s2 * 4 + lq];
            const uint2 q3 = base[(size_t)s3 * 4 + lq];
            ACC4(q0); ACC4(q1); ACC4(q2); ACC4(q3);
        }
        for (; i < end; i += 2) {
            const uint2 qq = base[(size_t)lidx[i] * 4 + lq];
            ACC4(qq);
        }
    } else {
        const int* gp = col_idx + base_off;
        for (; i + 14 < end; i += 16) {
            const int s0 = gp[i];
            const int s1 = gp[i + 2];
            const int s2 = gp[i + 4];
            const int s3 = gp[i + 6];
            const int s4 = gp[i + 8];
            const int s5 = gp[i + 10];
            const int s6 = gp[i + 12];
            const int s7 = gp[i + 14];
            const uint2 q0 = base[(size_t)s0 * 4 + lq];
            const uint2 q1 = base[(size_t)s1 * 4 + lq];
            const uint2 q2 = base[(size_t)s2 * 4 + lq];
            const uint2 q3 = base[(size_t)s3 * 4 + lq];
            const uint2 q4 = base[(size_t)s4 * 4 + lq];
            const uint2 q5 = base[(size_t)s5 * 4 + lq];
            const uint2 q6 = base[(size_t)s6 * 4 + lq];
            const uint2 q7 = base[(size_t)s7 * 4 + lq];
            ACC4(q0); ACC4(q1); ACC4(q2); ACC4(q3);
            ACC4(q4); ACC4(q5); ACC4(q6); ACC4(q7);
        }
        for (; i < end; i += 2) {
            const uint2 qq = base[(size_t)gp[i] * 4 + lq];
            ACC4(qq);
        }
    }
    a0 += __shfl_xor(a0, 4, 64); a1 += __shfl_xor(a1, 4, 64);
    a2 += __shfl_xor(a2, 4, 64); a3 += __shfl_xor(a3, 4, 64);
    if (half == 0) {
        const float dv = dinv[v];
        const float4 bb = ((const float4*)b2)[lq];
        float* hp = &hs[n][lq * 4];
        hp[0] = fmaxf(fmaf(a0, dv, bb.x), 0.0f);
        hp[1] = fmaxf(fmaf(a1, dv, bb.y), 0.0f);
        hp[2] = fmaxf(fmaf(a2, dv, bb.z), 0.0f);
        hp[3] = fmaxf(fmaf(a3, dv, bb.w), 0.0f);
    }
    __syncthreads();
    if (tid < P_NODES) {
        const int vv = v0 + tid;
        float lg[NC];
#pragma unroll
        for (int j = 0; j < NC; ++j) lg[j] = bcs[j];
#pragma unroll
        for (int k = 0; k < H2; ++k) {
            const float hk = hs[tid][k];
#pragma unroll
            for (int j = 0; j < NC; ++j)
                lg[j] = fmaf(hk, Wcs[k * NC + j], lg[j]);
        }
        float m = lg[0];
#pragma unroll
        for (int j = 1; j < NC; ++j) m = fmaxf(m, lg[j]);
        float s = 0.0f;
#pragma unroll
        for (int j = 0; j < NC; ++j) s += expf(lg[j] - m);
        const float lse = logf(s) + m;
        float4 o0, o1;
        o0.x = lg[0] - lse; o0.y = lg[1] - lse;
        o0.z = lg[2] - lse; o0.w = lg[3] - lse;
        o1.x = lg[4] - lse; o1.y = lg[5] - lse;
        o1.z = lg[6] - lse; o1.w = lg[7] - lse;
        float4* op = (float4*)(out + (size_t)vv * NC);
        op[0] = o0; op[1] = o1;
    }
}

// ---------------- host launch ----------------

extern "C" void kernel_launch(void* const* d_in, const int* in_sizes, int n_in,
                              void* d_out, int out_size, void* d_ws, size_t ws_size,
                              hipStream_t stream) {
    const float* x   = (const float*)d_in[0];
    const int*   ei  = (const int*)d_in[1];
    const float* W1  = (const float*)d_in[2];
    const float* b1  = (const float*)d_in[3];
    const float* W2  = (const float*)d_in[4];
    const float* b2  = (const float*)d_in[5];
    const float* Wc  = (const float*)d_in[6];
    const float* bc  = (const float*)d_in[7];
    float* out = (float*)d_out;

    // workspace layout (int units). ~41.2 MB total.
    int*   bucket_cursor = (int*)d_ws;                       // 1024 (NB2=782 used)
    float* dinv          = (float*)(bucket_cursor + 1024);   // 100000
    int*   degc          = (int*)dinv + 100000;              // 100096
    int*   bbase         = degc + 100096;                    // 1024 (783 used)
    int*   row_ptr       = bbase + 1024;                     // 100016 (100001 used)
    int*   col_idx       = row_ptr + 100016;                 // 3200000
    unsigned int* u1q    = (unsigned int*)(col_idx + 3200000); // 800000 dwords
    unsigned int* u2b    = u1q + 800000;                     // 800000 dwords
    int*   ebuf          = (int*)(u2b + 800000);             // NB2*BCAP2 = 4804608
    // y16 (bf16 x@W1, 6.4 MB) aliases col_idx (lifetimes disjoint).
    unsigned short* y16  = (unsigned short*)col_idx;         // 100096*32 shorts

    hipMemsetAsync(bucket_cursor, 0, 1024 * sizeof(int), stream);
    k_pre <<<NSB + 391, 512, 0, stream>>>(ei, x, W1, bucket_cursor, ebuf, y16);
    k_mid <<<391, 512, 0, stream>>>(ebuf, bucket_cursor, y16, degc, dinv, bbase, u1q);
    k_fuse1<<<NB2, 512, 0, stream>>>(ebuf, bucket_cursor, degc, bbase, u1q, b1, W2, row_ptr, col_idx, u2b);
    k_pull2f<<<N_NODES / P_NODES, 256, 0, stream>>>(row_ptr, col_idx, dinv, u2b, b2, Wc, bc, out);
}